// Round 11
// baseline (479.233 us; speedup 1.0000x reference)
//
#include <hip/hip_runtime.h>

constexpr int N_NODES = 50000;
constexpr int N_EDGES = 800000;
constexpr float BN_EPS = 1e-5f;
constexpr int BNA_BLOCKS = 256;

typedef __attribute__((ext_vector_type(8))) short short8;
typedef __attribute__((ext_vector_type(4))) float f32x4;

__device__ __forceinline__ float bf2f(ushort u) {
  union { uint i; float f; } v;
  v.i = ((uint)u) << 16;
  return v.f;
}
__device__ __forceinline__ ushort f2bf(float f) {
  union { float f; uint i; } v;
  v.f = f;
  uint r = v.i + 0x7fff + ((v.i >> 16) & 1);  // RNE
  return (ushort)(r >> 16);
}

// ---------------- degree / normalization ----------------
__global__ void k_deg(const int* __restrict__ row, int* __restrict__ deg) {
  int i = blockIdx.x * blockDim.x + threadIdx.x;
  int stride = gridDim.x * blockDim.x;
  for (; i < N_EDGES; i += stride) atomicAdd(&deg[row[i]], 1);
}

__global__ void k_disqrt(const int* __restrict__ deg, float* __restrict__ dis) {
  int i = blockIdx.x * blockDim.x + threadIdx.x;
  if (i < N_NODES) dis[i] = rsqrtf((float)(deg[i] + 1));
}

// ---------------- generic 256-wide scan pipeline (used for rs2) ----------------
__global__ void k_scan_part(const int* __restrict__ deg, int* __restrict__ bsum) {
  __shared__ int s[256];
  int t = threadIdx.x, i = blockIdx.x * 256 + t;
  s[t] = (i < N_NODES) ? deg[i] : 0;
  __syncthreads();
  for (int off = 128; off > 0; off >>= 1) {
    if (t < off) s[t] += s[t + off];
    __syncthreads();
  }
  if (t == 0) bsum[blockIdx.x] = s[0];
}

__global__ void k_scan_top(const int* __restrict__ bsum, int* __restrict__ boff, int nb) {
  __shared__ int s[256];
  int t = threadIdx.x;
  int v = (t < nb) ? bsum[t] : 0;
  s[t] = v;
  __syncthreads();
  for (int off = 1; off < 256; off <<= 1) {
    int x = (t >= off) ? s[t - off] : 0;
    __syncthreads();
    s[t] += x;
    __syncthreads();
  }
  if (t < nb) boff[t] = s[t] - v;  // exclusive
}

__global__ void k_scan_final(const int* __restrict__ deg, const int* __restrict__ boff,
                             int* __restrict__ row_start) {
  __shared__ int s[256];
  int t = threadIdx.x, i = blockIdx.x * 256 + t;
  int v = (i < N_NODES) ? deg[i] : 0;
  s[t] = v;
  __syncthreads();
  for (int off = 1; off < 256; off <<= 1) {
    int x = (t >= off) ? s[t - off] : 0;
    __syncthreads();
    s[t] += x;
    __syncthreads();
  }
  if (i < N_NODES) row_start[i] = boff[blockIdx.x] + s[t] - v;
  if (i == 0) row_start[N_NODES] = N_EDGES;
}

// ---------------- degree sort: two-level counting sort, no global atomics ----------
__global__ void k_blockhist(const int* __restrict__ deg, int* __restrict__ bh) {
  __shared__ int h[256];
  int t = threadIdx.x;
  h[t] = 0;
  __syncthreads();
  int i = blockIdx.x * 256 + t;
  if (i < N_NODES) atomicAdd(&h[min(deg[i], 255)], 1);
  __syncthreads();
  bh[blockIdx.x * 256 + t] = h[t];
}

// per-bin prefix over blocks (256 blocks = one bin each)
__global__ void k_binscanA(const int* __restrict__ bh, int* __restrict__ bhoff,
                           int* __restrict__ btot, int nb) {
  __shared__ int s[256];
  int b = blockIdx.x;   // bin
  int t = threadIdx.x;  // block index
  int v = (t < nb) ? bh[t * 256 + b] : 0;
  s[t] = v;
  __syncthreads();
  for (int off = 1; off < 256; off <<= 1) {
    int x = (t >= off) ? s[t - off] : 0;
    __syncthreads();
    s[t] += x;
    __syncthreads();
  }
  if (t < nb) bhoff[t * 256 + b] = s[t] - v;
  if (t == 255) btot[b] = s[255];
}

__global__ void k_binscanB(const int* __restrict__ btot, int* __restrict__ binoff) {
  __shared__ int s[256];
  int t = threadIdx.x;
  int v = btot[t];
  s[t] = v;
  __syncthreads();
  for (int off = 1; off < 256; off <<= 1) {
    int x = (t >= off) ? s[t - off] : 0;
    __syncthreads();
    s[t] += x;
    __syncthreads();
  }
  binoff[t] = s[t] - v;  // exclusive
}

// local ranks via LDS atomics; emits nodemap (spos->node), rank (node->spos), deg2
__global__ void k_sortscatter2(const int* __restrict__ deg, const int* __restrict__ binoff,
                               const int* __restrict__ bhoff, int* __restrict__ nodemap,
                               int* __restrict__ rank, int* __restrict__ deg2) {
  __shared__ int h[256];
  int t = threadIdx.x;
  h[t] = 0;
  __syncthreads();
  int i = blockIdx.x * 256 + t;
  if (i < N_NODES) {
    int d = deg[i];
    int b = min(d, 255);
    int r = atomicAdd(&h[b], 1);
    int pos = binoff[b] + bhoff[blockIdx.x * 256 + b] + r;
    nodemap[pos] = i;
    rank[i] = pos;
    deg2[pos] = d;
  }
}

__global__ void k_dis2(const int* __restrict__ nodemap, const float* __restrict__ dis,
                       float* __restrict__ dis2) {
  int i = blockIdx.x * 256 + threadIdx.x;
  if (i < N_NODES) dis2[i] = dis[nodemap[i]];
}

// edge scatter into sorted-space CSR (cs2 values = ORIGINAL node ids)
__global__ void k_scatter2(const int* __restrict__ row, const int* __restrict__ col,
                           const int* __restrict__ rs2, const int* __restrict__ rank,
                           int* __restrict__ fill, int* __restrict__ cs2) {
  int i = blockIdx.x * blockDim.x + threadIdx.x;
  int stride = gridDim.x * blockDim.x;
  for (; i < N_EDGES; i += stride) {
    int r = row[i];
    int pos = rs2[rank[r]] + atomicAdd(&fill[r], 1);
    cs2[pos] = col[i];
  }
}

// ---------------- W transpose to bf16: Wt[n][k] = bf16(W[k][n]) ----------------
__global__ void k_wt(const float* __restrict__ W, ushort* __restrict__ Wt, int K, int N) {
  int idx = blockIdx.x * 256 + threadIdx.x;
  if (idx >= K * N) return;
  int n = idx / K, k = idx % K;
  Wt[idx] = f2bf(W[(size_t)k * N + n]);
}

// ---------------- bf16 MFMA GEMM over SORTED rows -> chunk-major hsc ----------------
// APPLY_BN: A = pre_sorted (bf16, sorted rows), f=relu(a*scale+shift).
// else: A = x (f32, ORIGINAL rows) read via nm. Output row spos -> original node
// nm[spos]; hsc[(col/CW)*N + node]*CW + col%CW, scaled by dis2[spos].
template <int D, int CW, bool APPLY_BN>
__global__ __launch_bounds__(256, 2) void k_gemm_bf16(const void* __restrict__ Av,
                                                      const ushort* __restrict__ Wt,
                                                      const float* __restrict__ ss,
                                                      const float* __restrict__ dis2,
                                                      const int* __restrict__ nm,
                                                      ushort* __restrict__ hsc) {
  constexpr int BM = 128, BN = 128, BK = 32, K = 256;
  constexpr int LDP = BK + 8;
  __shared__ ushort As[BM * LDP];
  __shared__ ushort Bs[BN * LDP];
  const int tid = threadIdx.x;
  const int lane = tid & 63;
  const int wid = tid >> 6;
  const int wr = wid >> 1, wc = wid & 1;
  constexpr int NB = D / BN;
  const int rb = (blockIdx.x / NB) * BM;
  const int cb = (blockIdx.x % NB) * BN;

  f32x4 acc[4][4];
#pragma unroll
  for (int m = 0; m < 4; ++m)
#pragma unroll
    for (int n = 0; n < 4; ++n) acc[m][n] = (f32x4)(0.f);

  for (int kt = 0; kt < K; kt += BK) {
#pragma unroll
    for (int it = 0; it < 2; ++it) {
      int idx = tid + it * 256;
      int row = idx >> 2, kq = idx & 3;
      int gr = rb + row;
      if (gr >= N_NODES) gr = N_NODES - 1;
      float e[8];
      if constexpr (APPLY_BN) {
        const ushort* A = (const ushort*)Av;
        short8 v = *reinterpret_cast<const short8*>(&A[(size_t)gr * K + kt + kq * 8]);
#pragma unroll
        for (int q = 0; q < 8; ++q) {
          int k = kt + kq * 8 + q;
          e[q] = fmaxf(bf2f((ushort)v[q]) * ss[k] + ss[256 + k], 0.f);
        }
      } else {
        const float* A = (const float*)Av;
        int arow = nm[gr];
        const float4* src = reinterpret_cast<const float4*>(&A[(size_t)arow * K + kt + kq * 8]);
        float4 v0 = src[0], v1 = src[1];
        e[0] = v0.x; e[1] = v0.y; e[2] = v0.z; e[3] = v0.w;
        e[4] = v1.x; e[5] = v1.y; e[6] = v1.z; e[7] = v1.w;
      }
      short8 pk;
#pragma unroll
      for (int q = 0; q < 8; ++q) pk[q] = (short)f2bf(e[q]);
      *reinterpret_cast<short8*>(&As[row * LDP + kq * 8]) = pk;
    }
#pragma unroll
    for (int it = 0; it < 2; ++it) {
      int idx = tid + it * 256;
      int n = idx >> 2, kq = idx & 3;
      short8 v = *reinterpret_cast<const short8*>(&Wt[(size_t)(cb + n) * K + kt + kq * 8]);
      *reinterpret_cast<short8*>(&Bs[n * LDP + kq * 8]) = v;
    }
    __syncthreads();

    const int rl = lane & 15;
    const int kb = (lane >> 4) * 8;
    short8 af[4], bfr[4];
#pragma unroll
    for (int f = 0; f < 4; ++f) {
      af[f] = *reinterpret_cast<short8*>(&As[(wr * 64 + f * 16 + rl) * LDP + kb]);
      bfr[f] = *reinterpret_cast<short8*>(&Bs[(wc * 64 + f * 16 + rl) * LDP + kb]);
    }
#pragma unroll
    for (int m = 0; m < 4; ++m)
#pragma unroll
      for (int n = 0; n < 4; ++n)
        acc[m][n] = __builtin_amdgcn_mfma_f32_16x16x32_bf16(af[m], bfr[n], acc[m][n], 0, 0, 0);
    __syncthreads();
  }

  const int cl = lane & 15;
  const int rq = lane >> 4;
#pragma unroll
  for (int m = 0; m < 4; ++m) {
    int rbase = rb + wr * 64 + m * 16 + rq * 4;
#pragma unroll
    for (int j = 0; j < 4; ++j) {
      int row = rbase + j;
      if (row >= N_NODES) continue;
      float di = dis2[row];
      int node = nm[row];
#pragma unroll
      for (int n = 0; n < 4; ++n) {
        int col = cb + wc * 64 + n * 16 + cl;
        size_t addr = ((size_t)(col / CW) * N_NODES + node) * CW + (col % CW);
        hsc[addr] = f2bf(acc[m][n][j] * di);
      }
    }
  }
}

// ---------------- chunked agg, fully sorted-space ----------------
// hsc chunk-major [8][N][CW] (original-id rows, gather space); cs2 sorted CSR.
// Wave = NG consecutive spos x LPG lanes. Outputs pre_sorted[spos] (coalesced).
template <int CW, bool OUT_F32, int OUTD>
__global__ __launch_bounds__(256) void k_agg_sorted(const ushort* __restrict__ hsc,
                                                    const int* __restrict__ cs2,
                                                    const int* __restrict__ rs2,
                                                    const int* __restrict__ nm,
                                                    const float* __restrict__ dis2,
                                                    const float* __restrict__ bias,
                                                    void* __restrict__ outp) {
  constexpr int LPG = CW / 4;   // 8 (CW=32) / 4 (CW=16)
  constexpr int NG = 64 / LPG;  // 8 / 16
  const int chunk = blockIdx.x & 7;
  const int wave = threadIdx.x >> 6;
  const int lane = threadIdx.x & 63;
  const int g = lane / LPG;
  const int k = lane & (LPG - 1);
  const int spos = (blockIdx.x >> 3) * (4 * NG) + wave * NG + g;
  const bool alive = spos < N_NODES;
  const int sp = alive ? spos : N_NODES - 1;
  const int node = nm[sp];
  const int s = rs2[sp];
  const int deg = alive ? (rs2[sp + 1] - s) : 0;
  const ushort* bc = hsc + (size_t)chunk * N_NODES * CW + k * 4;

  // self contribution
  ushort4 sv = *reinterpret_cast<const ushort4*>(&bc[(size_t)node * CW]);
  float a0 = bf2f(sv.x), a1 = bf2f(sv.y), a2 = bf2f(sv.z), a3 = bf2f(sv.w);

  int jb = 0;
  for (; jb + LPG <= deg; jb += LPG) {
    int idxk = __builtin_nontemporal_load(&cs2[s + jb + k]);
    ushort4 v[LPG];
#pragma unroll
    for (int st = 0; st < LPG; ++st) {
      int c = __shfl(idxk, g * LPG + st);
      v[st] = *reinterpret_cast<const ushort4*>(&bc[(size_t)((uint)c * CW)]);
    }
#pragma unroll
    for (int st = 0; st < LPG; ++st) {
      a0 += bf2f(v[st].x);
      a1 += bf2f(v[st].y);
      a2 += bf2f(v[st].z);
      a3 += bf2f(v[st].w);
    }
  }
  if (jb < deg) {  // tail batch, weight-folded
    int idxk = (jb + k < deg) ? __builtin_nontemporal_load(&cs2[s + jb + k]) : 0;
    ushort4 v[LPG];
#pragma unroll
    for (int st = 0; st < LPG; ++st) {
      int c = __shfl(idxk, g * LPG + st);
      v[st] = *reinterpret_cast<const ushort4*>(&bc[(size_t)((uint)c * CW)]);
    }
#pragma unroll
    for (int st = 0; st < LPG; ++st) {
      float w = (jb + st < deg) ? 1.f : 0.f;
      a0 = fmaf(w, bf2f(v[st].x), a0);
      a1 = fmaf(w, bf2f(v[st].y), a1);
      a2 = fmaf(w, bf2f(v[st].z), a2);
      a3 = fmaf(w, bf2f(v[st].w), a3);
    }
  }

  if (alive) {
    float di = dis2[spos];
    float4 b = *reinterpret_cast<const float4*>(&bias[chunk * CW + k * 4]);
    float o0 = a0 * di + b.x, o1 = a1 * di + b.y;
    float o2 = a2 * di + b.z, o3 = a3 * di + b.w;
    if constexpr (OUT_F32) {
      float* out = (float*)outp;
      float4 o = {o0, o1, o2, o3};
      *reinterpret_cast<float4*>(&out[(size_t)spos * OUTD + chunk * CW + k * 4]) = o;
    } else {
      ushort* out = (ushort*)outp;
      ushort4 o;
      o.x = f2bf(o0);
      o.y = f2bf(o1);
      o.z = f2bf(o2);
      o.w = f2bf(o3);
      *reinterpret_cast<ushort4*>(&out[(size_t)spos * OUTD + chunk * CW + k * 4]) = o;
    }
  }
}

// ---------------- log_softmax: read sorted, write original ----------------
__global__ __launch_bounds__(256) void k_lsm(const float* __restrict__ pre2,
                                             const int* __restrict__ nm,
                                             float* __restrict__ out) {
  int spos = (blockIdx.x * 256 + threadIdx.x) >> 6;
  if (spos >= N_NODES) return;
  int lane = threadIdx.x & 63;
  float2 v = *reinterpret_cast<const float2*>(&pre2[(size_t)spos * 128 + lane * 2]);
  float m = fmaxf(v.x, v.y);
#pragma unroll
  for (int o = 1; o < 64; o <<= 1) m = fmaxf(m, __shfl_xor(m, o));
  float sum = __expf(v.x - m) + __expf(v.y - m);
#pragma unroll
  for (int o = 1; o < 64; o <<= 1) sum += __shfl_xor(sum, o);
  float ls = m + logf(sum);
  int node = nm[spos];
  float2 o2 = {v.x - ls, v.y - ls};
  *reinterpret_cast<float2*>(&out[(size_t)node * 128 + lane * 2]) = o2;
}

// ---------------- batchnorm stats: three-phase, atomic-free ----------------
__global__ __launch_bounds__(256) void k_bnstatsA(const ushort* __restrict__ pre,
                                                  float* __restrict__ partial) {
  int t = threadIdx.x;
  int rsub = t >> 7;
  int cp = (t & 127) * 2;
  float s0 = 0.f, s1 = 0.f, q0 = 0.f, q1 = 0.f;
  for (int r = blockIdx.x * 2 + rsub; r < N_NODES; r += BNA_BLOCKS * 2) {
    ushort2 v = *reinterpret_cast<const ushort2*>(&pre[(size_t)r * 256 + cp]);
    float f0 = bf2f(v.x), f1 = bf2f(v.y);
    s0 += f0;
    q0 += f0 * f0;
    s1 += f1;
    q1 += f1 * f1;
  }
  __shared__ float lsum[256], lsq[256];
  if (rsub) {
    lsum[cp] = s0;
    lsum[cp + 1] = s1;
    lsq[cp] = q0;
    lsq[cp + 1] = q1;
  }
  __syncthreads();
  if (!rsub) {
    float* p = &partial[(size_t)blockIdx.x * 512];
    p[cp] = s0 + lsum[cp];
    p[cp + 1] = s1 + lsum[cp + 1];
    p[256 + cp] = q0 + lsq[cp];
    p[256 + cp + 1] = q1 + lsq[cp + 1];
  }
}

__global__ __launch_bounds__(512) void k_bnstatsB(const float* __restrict__ partial,
                                                  float* __restrict__ p2) {
  int t = threadIdx.x, b = blockIdx.x;
  float a = 0.f;
#pragma unroll 8
  for (int r = 0; r < BNA_BLOCKS / 8; ++r)
    a += partial[(size_t)(b * (BNA_BLOCKS / 8) + r) * 512 + t];
  p2[(size_t)b * 512 + t] = a;
}

__global__ void k_bnfinal(const float* __restrict__ p2, const float* __restrict__ gamma,
                          const float* __restrict__ beta, float* __restrict__ ss) {
  int t = threadIdx.x;
  float sum = 0.f, sq = 0.f;
#pragma unroll
  for (int b = 0; b < 8; ++b) {
    sum += p2[(size_t)b * 512 + t];
    sq += p2[(size_t)b * 512 + 256 + t];
  }
  float mu = sum * (1.f / N_NODES);
  float var = sq * (1.f / N_NODES) - mu * mu;
  float sc = gamma[t] * rsqrtf(var + BN_EPS);
  ss[t] = sc;
  ss[256 + t] = beta[t] - mu * sc;
}

// ---------------- launcher ----------------
extern "C" void kernel_launch(void* const* d_in, const int* in_sizes, int n_in,
                              void* d_out, int out_size, void* d_ws, size_t ws_size,
                              hipStream_t stream) {
  const float* x = (const float*)d_in[0];
  const int* erow = (const int*)d_in[1];
  const int* ecol = erow + N_EDGES;
  const float* W0 = (const float*)d_in[2];
  const float* b0 = (const float*)d_in[3];
  const float* W1 = (const float*)d_in[4];
  const float* b1 = (const float*)d_in[5];
  const float* W2 = (const float*)d_in[6];
  const float* b2 = (const float*)d_in[7];
  const float* g0 = (const float*)d_in[8];
  const float* be0 = (const float*)d_in[9];
  const float* g1 = (const float*)d_in[10];
  const float* be1 = (const float*)d_in[11];
  float* out = (float*)d_out;

  char* ws = (char*)d_ws;
  size_t off = 0;
  auto take = [&](size_t bytes) {
    char* p = ws + off;
    off = (off + bytes + 255) & ~(size_t)255;
    return p;
  };
  int* deg = (int*)take(N_NODES * 4);
  int* fill = (int*)take(N_NODES * 4);
  size_t zero_bytes = off;  // deg/fill must start at 0 each call
  int nb = (N_NODES + 255) / 256;  // 196
  int* bh = (int*)take((size_t)nb * 256 * 4);
  int* bhoff = (int*)take((size_t)nb * 256 * 4);
  int* btot = (int*)take(256 * 4);
  int* binoff = (int*)take(256 * 4);
  int* nodemap = (int*)take(N_NODES * 4);
  int* rank = (int*)take(N_NODES * 4);
  int* deg2 = (int*)take(N_NODES * 4);
  int* rs2 = (int*)take((N_NODES + 1) * 4);
  float* bnpart = (float*)take((size_t)BNA_BLOCKS * 512 * 4);
  float* bnpart2 = (float*)take(8 * 512 * 4);
  float* dis = (float*)take(N_NODES * 4);
  float* dis2 = (float*)take(N_NODES * 4);
  int* bsum = (int*)take(256 * 4);
  int* boff = (int*)take(256 * 4);
  float* ss0 = (float*)take(512 * 4);
  float* ss1 = (float*)take(512 * 4);
  ushort* Wt0 = (ushort*)take(256 * 256 * 2);
  ushort* Wt1 = (ushort*)take(256 * 256 * 2);
  ushort* Wt2 = (ushort*)take(256 * 128 * 2);
  int* cs2 = (int*)take((size_t)N_EDGES * 4);
  ushort* hsc = (ushort*)take((size_t)N_NODES * 256 * 2);      // chunk-major (orig ids)
  ushort* pre_s = (ushort*)take((size_t)N_NODES * 256 * 2);    // sorted rows, bf16
  float* pre2_s = (float*)take((size_t)N_NODES * 128 * 4);     // sorted rows, f32 logits
  if (off > ws_size) return;

  hipMemsetAsync(d_ws, 0, zero_bytes, stream);

  k_deg<<<1024, 256, 0, stream>>>(erow, deg);
  k_disqrt<<<nb, 256, 0, stream>>>(deg, dis);

  // degree sort -> nodemap/rank/deg2 -> rs2 -> cs2
  k_blockhist<<<nb, 256, 0, stream>>>(deg, bh);
  k_binscanA<<<256, 256, 0, stream>>>(bh, bhoff, btot, nb);
  k_binscanB<<<1, 256, 0, stream>>>(btot, binoff);
  k_sortscatter2<<<nb, 256, 0, stream>>>(deg, binoff, bhoff, nodemap, rank, deg2);
  k_dis2<<<nb, 256, 0, stream>>>(nodemap, dis, dis2);
  k_scan_part<<<nb, 256, 0, stream>>>(deg2, bsum);
  k_scan_top<<<1, 256, 0, stream>>>(bsum, boff, nb);
  k_scan_final<<<nb, 256, 0, stream>>>(deg2, boff, rs2);
  k_scatter2<<<1024, 256, 0, stream>>>(erow, ecol, rs2, rank, fill, cs2);

  k_wt<<<(256 * 256 + 255) / 256, 256, 0, stream>>>(W0, Wt0, 256, 256);
  k_wt<<<(256 * 256 + 255) / 256, 256, 0, stream>>>(W1, Wt1, 256, 256);
  k_wt<<<(256 * 128 + 255) / 256, 256, 0, stream>>>(W2, Wt2, 256, 128);

  int mblocks = (N_NODES + 127) / 128;         // 391
  int agg32_grid = ((N_NODES + 31) / 32) * 8;  // 12504
  int agg16_grid = ((N_NODES + 63) / 64) * 8;  // 6256
  int lsm_grid = (N_NODES * 64 + 255) / 256;   // 12500
  // layer 0 (A = x via nodemap)
  k_gemm_bf16<256, 32, false><<<mblocks * 2, 256, 0, stream>>>(x, Wt0, nullptr, dis2, nodemap, hsc);
  k_agg_sorted<32, false, 256><<<agg32_grid, 256, 0, stream>>>(hsc, cs2, rs2, nodemap, dis2, b0, pre_s);
  k_bnstatsA<<<BNA_BLOCKS, 256, 0, stream>>>(pre_s, bnpart);
  k_bnstatsB<<<8, 512, 0, stream>>>(bnpart, bnpart2);
  k_bnfinal<<<1, 256, 0, stream>>>(bnpart2, g0, be0, ss0);
  // layer 1 (A = pre_s, sorted rows)
  k_gemm_bf16<256, 32, true><<<mblocks * 2, 256, 0, stream>>>(pre_s, Wt1, ss0, dis2, nodemap, hsc);
  k_agg_sorted<32, false, 256><<<agg32_grid, 256, 0, stream>>>(hsc, cs2, rs2, nodemap, dis2, b1, pre_s);
  k_bnstatsA<<<BNA_BLOCKS, 256, 0, stream>>>(pre_s, bnpart);
  k_bnstatsB<<<8, 512, 0, stream>>>(bnpart, bnpart2);
  k_bnfinal<<<1, 256, 0, stream>>>(bnpart2, g1, be1, ss1);
  // layer 2: GEMM -> chunked agg (f32 logits, sorted) -> log_softmax (unsort)
  k_gemm_bf16<128, 16, true><<<mblocks, 256, 0, stream>>>(pre_s, Wt2, ss1, dis2, nodemap, hsc);
  k_agg_sorted<16, true, 128><<<agg16_grid, 256, 0, stream>>>(hsc, cs2, rs2, nodemap, dis2, b2, pre2_s);
  k_lsm<<<lsm_grid, 256, 0, stream>>>(pre2_s, nodemap, out);
}

// Round 12
// 371.674 us; speedup vs baseline: 1.2894x; 1.2894x over previous
//
#include <hip/hip_runtime.h>

constexpr int N_NODES = 50000;
constexpr int N_EDGES = 800000;
constexpr float BN_EPS = 1e-5f;
constexpr int BNA_BLOCKS = 256;

typedef __attribute__((ext_vector_type(8))) short short8;
typedef __attribute__((ext_vector_type(4))) float f32x4;

__device__ __forceinline__ float bf2f(ushort u) {
  union { uint i; float f; } v;
  v.i = ((uint)u) << 16;
  return v.f;
}
__device__ __forceinline__ ushort f2bf(float f) {
  union { float f; uint i; } v;
  v.f = f;
  uint r = v.i + 0x7fff + ((v.i >> 16) & 1);  // RNE
  return (ushort)(r >> 16);
}

// ---------------- degree / normalization ----------------
__global__ void k_deg(const int* __restrict__ row, int* __restrict__ deg) {
  int i = blockIdx.x * blockDim.x + threadIdx.x;
  int stride = gridDim.x * blockDim.x;
  for (; i < N_EDGES; i += stride) atomicAdd(&deg[row[i]], 1);
}

__global__ void k_disqrt(const int* __restrict__ deg, float* __restrict__ dis) {
  int i = blockIdx.x * blockDim.x + threadIdx.x;
  if (i < N_NODES) dis[i] = rsqrtf((float)(deg[i] + 1));
}

// ---------------- CSR build: 3-phase scan + scatter ----------------
__global__ void k_scan_part(const int* __restrict__ deg, int* __restrict__ bsum) {
  __shared__ int s[256];
  int t = threadIdx.x, i = blockIdx.x * 256 + t;
  s[t] = (i < N_NODES) ? deg[i] : 0;
  __syncthreads();
  for (int off = 128; off > 0; off >>= 1) {
    if (t < off) s[t] += s[t + off];
    __syncthreads();
  }
  if (t == 0) bsum[blockIdx.x] = s[0];
}

__global__ void k_scan_top(const int* __restrict__ bsum, int* __restrict__ boff, int nb) {
  __shared__ int s[256];
  int t = threadIdx.x;
  int v = (t < nb) ? bsum[t] : 0;
  s[t] = v;
  __syncthreads();
  for (int off = 1; off < 256; off <<= 1) {
    int x = (t >= off) ? s[t - off] : 0;
    __syncthreads();
    s[t] += x;
    __syncthreads();
  }
  if (t < nb) boff[t] = s[t] - v;  // exclusive
}

__global__ void k_scan_final(const int* __restrict__ deg, const int* __restrict__ boff,
                             int* __restrict__ row_start) {
  __shared__ int s[256];
  int t = threadIdx.x, i = blockIdx.x * 256 + t;
  int v = (i < N_NODES) ? deg[i] : 0;
  s[t] = v;
  __syncthreads();
  for (int off = 1; off < 256; off <<= 1) {
    int x = (t >= off) ? s[t - off] : 0;
    __syncthreads();
    s[t] += x;
    __syncthreads();
  }
  if (i < N_NODES) row_start[i] = boff[blockIdx.x] + s[t] - v;
  if (i == 0) row_start[N_NODES] = N_EDGES;
}

__global__ void k_scatter(const int* __restrict__ row, const int* __restrict__ col,
                          const int* __restrict__ row_start, int* __restrict__ fill,
                          int* __restrict__ col_sorted) {
  int i = blockIdx.x * blockDim.x + threadIdx.x;
  int stride = gridDim.x * blockDim.x;
  for (; i < N_EDGES; i += stride) {
    int r = row[i];
    int pos = row_start[r] + atomicAdd(&fill[r], 1);
    col_sorted[pos] = col[i];
  }
}

// ---------------- W transpose to bf16: Wt[n][k] = bf16(W[k][n]) ----------------
__global__ void k_wt(const float* __restrict__ W, ushort* __restrict__ Wt, int K, int N) {
  int idx = blockIdx.x * 256 + threadIdx.x;
  if (idx >= K * N) return;
  int n = idx / K, k = idx % K;
  Wt[idx] = f2bf(W[(size_t)k * N + n]);
}

// ---------------- bf16 MFMA GEMM: hs = bf16( f(A) @ W * d_isqrt ) ----------------
// APPLY_BN: A is bf16 [N,256], f(A)=relu(A*scale+shift). else A fp32 [N,256], f=id.
// Wt: [D,256] bf16 (W transposed); hs: [N_NODES,D] bf16 row-major.
// BM=128, BN=D, BK=32. D=256: 512 thr = 8 waves (2x4), A staged ONCE per row-tile.
// D=128: 256 thr = 4 waves (2x2) — identical to the proven r6 kernel.
template <int D, bool APPLY_BN>
__global__ __launch_bounds__(128 * (D / 64)) void k_gemm_bf16(const void* __restrict__ Av,
                                                              const ushort* __restrict__ Wt,
                                                              const float* __restrict__ ss,
                                                              const float* __restrict__ dis,
                                                              ushort* __restrict__ hs) {
  constexpr int THREADS = 128 * (D / 64);  // 512 (D=256) / 256 (D=128)
  constexpr int BM = 128, BK = 32, K = 256;
  constexpr int WC = D / 64;  // wave cols: 4 / 2
  constexpr int LDP = BK + 8;  // 40 bf16 (80B) stride: conflict-free b128 frags
  __shared__ ushort As[BM * LDP];
  __shared__ ushort Bs[D * LDP];
  const int tid = threadIdx.x;
  const int lane = tid & 63;
  const int wid = tid >> 6;
  const int wr = wid / WC, wc = wid % WC;
  const int rb = blockIdx.x * BM;

  f32x4 acc[4][4];
#pragma unroll
  for (int m = 0; m < 4; ++m)
#pragma unroll
    for (int n = 0; n < 4; ++n) acc[m][n] = (f32x4)(0.f);

  for (int kt = 0; kt < K; kt += BK) {
    // stage A: 128 rows x 32 k = 512 tasks of 8 elems
#pragma unroll
    for (int it = 0; it < 512 / THREADS; ++it) {
      int idx = tid + it * THREADS;
      int row = idx >> 2, kq = idx & 3;
      int gr = rb + row;
      if (gr >= N_NODES) gr = N_NODES - 1;
      float e[8];
      if constexpr (APPLY_BN) {
        const ushort* A = (const ushort*)Av;
        short8 v = *reinterpret_cast<const short8*>(&A[(size_t)gr * K + kt + kq * 8]);
#pragma unroll
        for (int q = 0; q < 8; ++q) {
          int k = kt + kq * 8 + q;
          e[q] = fmaxf(bf2f((ushort)v[q]) * ss[k] + ss[256 + k], 0.f);
        }
      } else {
        const float* A = (const float*)Av;
        const float4* src = reinterpret_cast<const float4*>(&A[(size_t)gr * K + kt + kq * 8]);
        float4 v0 = src[0], v1 = src[1];
        e[0] = v0.x; e[1] = v0.y; e[2] = v0.z; e[3] = v0.w;
        e[4] = v1.x; e[5] = v1.y; e[6] = v1.z; e[7] = v1.w;
      }
      short8 pk;
#pragma unroll
      for (int q = 0; q < 8; ++q) pk[q] = (short)f2bf(e[q]);
      *reinterpret_cast<short8*>(&As[row * LDP + kq * 8]) = pk;
    }
    // stage B from Wt (bf16, k-contiguous): D rows x 32 k = D*4 tasks
#pragma unroll
    for (int it = 0; it < D * 4 / THREADS; ++it) {
      int idx = tid + it * THREADS;
      int n = idx >> 2, kq = idx & 3;
      short8 v = *reinterpret_cast<const short8*>(&Wt[(size_t)n * K + kt + kq * 8]);
      *reinterpret_cast<short8*>(&Bs[n * LDP + kq * 8]) = v;
    }
    __syncthreads();

    const int rl = lane & 15;
    const int kb = (lane >> 4) * 8;
    short8 af[4], bfr[4];
#pragma unroll
    for (int f = 0; f < 4; ++f) {
      af[f] = *reinterpret_cast<short8*>(&As[(wr * 64 + f * 16 + rl) * LDP + kb]);
      bfr[f] = *reinterpret_cast<short8*>(&Bs[(wc * 64 + f * 16 + rl) * LDP + kb]);
    }
#pragma unroll
    for (int m = 0; m < 4; ++m)
#pragma unroll
      for (int n = 0; n < 4; ++n)
        acc[m][n] = __builtin_amdgcn_mfma_f32_16x16x32_bf16(af[m], bfr[n], acc[m][n], 0, 0, 0);
    __syncthreads();
  }

  // epilogue: *dis[row], cvt bf16, store. C frag: col=lane&15, row=(lane>>4)*4+j.
  const int cl = lane & 15;
  const int rq = lane >> 4;
#pragma unroll
  for (int m = 0; m < 4; ++m) {
    int rbase = rb + wr * 64 + m * 16 + rq * 4;
#pragma unroll
    for (int j = 0; j < 4; ++j) {
      int row = rbase + j;
      if (row >= N_NODES) continue;
      float di = dis[row];
#pragma unroll
      for (int n = 0; n < 4; ++n) {
        int col = wc * 64 + n * 16 + cl;
        hs[(size_t)row * D + col] = f2bf(acc[m][n][j] * di);
      }
    }
  }
}

// ---------------- aggregation (bf16 gather): pre = bf16(dis*(self+sum_nbr)+b) -------
// wave per node, lane = 4 cols (D=256); gather loop unrolled x8.
__global__ __launch_bounds__(256) void k_agg_bf16(const ushort* __restrict__ hs,
                                                  const int* __restrict__ cs,
                                                  const int* __restrict__ rs,
                                                  const float* __restrict__ dis,
                                                  const float* __restrict__ bias,
                                                  ushort* __restrict__ pre) {
  int gw = (blockIdx.x * 256 + threadIdx.x) >> 6;
  if (gw >= N_NODES) return;
  int lane = threadIdx.x & 63;
  size_t coff = (size_t)lane * 4;
  ushort4 sv = *reinterpret_cast<const ushort4*>(&hs[(size_t)gw * 256 + coff]);
  float a0 = bf2f(sv.x), a1 = bf2f(sv.y), a2 = bf2f(sv.z), a3 = bf2f(sv.w);
  int s = rs[gw], e = rs[gw + 1];
  for (int base = s; base < e; base += 64) {
    int nav = min(64, e - base);
    int idx = (base + lane < e) ? cs[base + lane] : 0;
    int j = 0;
    for (; j + 7 < nav; j += 8) {
      ushort4 v[8];
#pragma unroll
      for (int u = 0; u < 8; ++u) {
        int c = __shfl(idx, j + u);
        v[u] = *reinterpret_cast<const ushort4*>(&hs[(size_t)c * 256 + coff]);
      }
#pragma unroll
      for (int u = 0; u < 8; ++u) {
        a0 += bf2f(v[u].x);
        a1 += bf2f(v[u].y);
        a2 += bf2f(v[u].z);
        a3 += bf2f(v[u].w);
      }
    }
    for (; j < nav; ++j) {
      int c0 = __shfl(idx, j);
      ushort4 v0 = *reinterpret_cast<const ushort4*>(&hs[(size_t)c0 * 256 + coff]);
      a0 += bf2f(v0.x);
      a1 += bf2f(v0.y);
      a2 += bf2f(v0.z);
      a3 += bf2f(v0.w);
    }
  }
  float di = dis[gw];
  float4 b = *reinterpret_cast<const float4*>(&bias[lane * 4]);
  ushort4 o;
  o.x = f2bf(a0 * di + b.x);
  o.y = f2bf(a1 * di + b.y);
  o.z = f2bf(a2 * di + b.z);
  o.w = f2bf(a3 * di + b.w);
  *reinterpret_cast<ushort4*>(&pre[(size_t)gw * 256 + coff]) = o;
}

// layer-3 aggregation fused with log_softmax, D=128, wave per node (lane: 2 cols)
__global__ __launch_bounds__(256) void k_agg_lsm_bf16(const ushort* __restrict__ hs,
                                                      const int* __restrict__ cs,
                                                      const int* __restrict__ rs,
                                                      const float* __restrict__ dis,
                                                      const float* __restrict__ bias,
                                                      float* __restrict__ out) {
  int gw = (blockIdx.x * 256 + threadIdx.x) >> 6;
  if (gw >= N_NODES) return;
  int lane = threadIdx.x & 63;
  ushort2 sv = *reinterpret_cast<const ushort2*>(&hs[(size_t)gw * 128 + lane * 2]);
  float a0 = bf2f(sv.x), a1 = bf2f(sv.y);
  int s = rs[gw], e = rs[gw + 1];
  for (int base = s; base < e; base += 64) {
    int nav = min(64, e - base);
    int idx = (base + lane < e) ? cs[base + lane] : 0;
    int j = 0;
    for (; j + 7 < nav; j += 8) {
      ushort2 v[8];
#pragma unroll
      for (int u = 0; u < 8; ++u) {
        int c = __shfl(idx, j + u);
        v[u] = *reinterpret_cast<const ushort2*>(&hs[(size_t)c * 128 + lane * 2]);
      }
#pragma unroll
      for (int u = 0; u < 8; ++u) {
        a0 += bf2f(v[u].x);
        a1 += bf2f(v[u].y);
      }
    }
    for (; j < nav; ++j) {
      int c0 = __shfl(idx, j);
      ushort2 v0 = *reinterpret_cast<const ushort2*>(&hs[(size_t)c0 * 128 + lane * 2]);
      a0 += bf2f(v0.x);
      a1 += bf2f(v0.y);
    }
  }
  float di = dis[gw];
  float2 b = *reinterpret_cast<const float2*>(&bias[lane * 2]);
  float v0 = a0 * di + b.x, v1 = a1 * di + b.y;
  float m = fmaxf(v0, v1);
#pragma unroll
  for (int o = 1; o < 64; o <<= 1) m = fmaxf(m, __shfl_xor(m, o));
  float sum = __expf(v0 - m) + __expf(v1 - m);
#pragma unroll
  for (int o = 1; o < 64; o <<= 1) sum += __shfl_xor(sum, o);
  float ls = m + logf(sum);
  float2 o2 = {v0 - ls, v1 - ls};
  *reinterpret_cast<float2*>(&out[(size_t)gw * 128 + lane * 2]) = o2;
}

// ---------------- batchnorm stats: three-phase, atomic-free ----------------
__global__ __launch_bounds__(256) void k_bnstatsA(const ushort* __restrict__ pre,
                                                  float* __restrict__ partial) {
  int t = threadIdx.x;
  int rsub = t >> 7;
  int cp = (t & 127) * 2;
  float s0 = 0.f, s1 = 0.f, q0 = 0.f, q1 = 0.f;
  for (int r = blockIdx.x * 2 + rsub; r < N_NODES; r += BNA_BLOCKS * 2) {
    ushort2 v = *reinterpret_cast<const ushort2*>(&pre[(size_t)r * 256 + cp]);
    float f0 = bf2f(v.x), f1 = bf2f(v.y);
    s0 += f0;
    q0 += f0 * f0;
    s1 += f1;
    q1 += f1 * f1;
  }
  __shared__ float lsum[256], lsq[256];
  if (rsub) {
    lsum[cp] = s0;
    lsum[cp + 1] = s1;
    lsq[cp] = q0;
    lsq[cp + 1] = q1;
  }
  __syncthreads();
  if (!rsub) {
    float* p = &partial[(size_t)blockIdx.x * 512];
    p[cp] = s0 + lsum[cp];
    p[cp + 1] = s1 + lsum[cp + 1];
    p[256 + cp] = q0 + lsq[cp];
    p[256 + cp + 1] = q1 + lsq[cp + 1];
  }
}

__global__ __launch_bounds__(512) void k_bnstatsB(const float* __restrict__ partial,
                                                  float* __restrict__ p2) {
  int t = threadIdx.x, b = blockIdx.x;
  float a = 0.f;
#pragma unroll 8
  for (int r = 0; r < BNA_BLOCKS / 8; ++r)
    a += partial[(size_t)(b * (BNA_BLOCKS / 8) + r) * 512 + t];
  p2[(size_t)b * 512 + t] = a;
}

__global__ void k_bnfinal(const float* __restrict__ p2, const float* __restrict__ gamma,
                          const float* __restrict__ beta, float* __restrict__ ss) {
  int t = threadIdx.x;
  float sum = 0.f, sq = 0.f;
#pragma unroll
  for (int b = 0; b < 8; ++b) {
    sum += p2[(size_t)b * 512 + t];
    sq += p2[(size_t)b * 512 + 256 + t];
  }
  float mu = sum * (1.f / N_NODES);
  float var = sq * (1.f / N_NODES) - mu * mu;
  float sc = gamma[t] * rsqrtf(var + BN_EPS);
  ss[t] = sc;
  ss[256 + t] = beta[t] - mu * sc;
}

// ---------------- launcher ----------------
extern "C" void kernel_launch(void* const* d_in, const int* in_sizes, int n_in,
                              void* d_out, int out_size, void* d_ws, size_t ws_size,
                              hipStream_t stream) {
  const float* x = (const float*)d_in[0];
  const int* erow = (const int*)d_in[1];
  const int* ecol = erow + N_EDGES;
  const float* W0 = (const float*)d_in[2];
  const float* b0 = (const float*)d_in[3];
  const float* W1 = (const float*)d_in[4];
  const float* b1 = (const float*)d_in[5];
  const float* W2 = (const float*)d_in[6];
  const float* b2 = (const float*)d_in[7];
  const float* g0 = (const float*)d_in[8];
  const float* be0 = (const float*)d_in[9];
  const float* g1 = (const float*)d_in[10];
  const float* be1 = (const float*)d_in[11];
  float* out = (float*)d_out;

  char* ws = (char*)d_ws;
  size_t off = 0;
  auto take = [&](size_t bytes) {
    char* p = ws + off;
    off = (off + bytes + 255) & ~(size_t)255;
    return p;
  };
  int* deg = (int*)take(N_NODES * 4);
  int* fill = (int*)take(N_NODES * 4);
  size_t zero_bytes = off;  // deg+fill must start at 0 each call
  float* bnpart = (float*)take((size_t)BNA_BLOCKS * 512 * 4);
  float* bnpart2 = (float*)take(8 * 512 * 4);
  float* dis = (float*)take(N_NODES * 4);
  int* row_start = (int*)take((N_NODES + 1) * 4);
  int* bsum = (int*)take(256 * 4);
  int* boff = (int*)take(256 * 4);
  float* ss0 = (float*)take(512 * 4);
  float* ss1 = (float*)take(512 * 4);
  ushort* Wt0 = (ushort*)take(256 * 256 * 2);
  ushort* Wt1 = (ushort*)take(256 * 256 * 2);
  ushort* Wt2 = (ushort*)take(256 * 128 * 2);
  int* col_sorted = (int*)take((size_t)N_EDGES * 4);
  ushort* hs = (ushort*)take((size_t)N_NODES * 256 * 2);
  ushort* pre = (ushort*)take((size_t)N_NODES * 256 * 2);
  if (off > ws_size) return;

  hipMemsetAsync(d_ws, 0, zero_bytes, stream);

  k_deg<<<1024, 256, 0, stream>>>(erow, deg);
  k_disqrt<<<(N_NODES + 255) / 256, 256, 0, stream>>>(deg, dis);
  int nb = (N_NODES + 255) / 256;  // 196
  k_scan_part<<<nb, 256, 0, stream>>>(deg, bsum);
  k_scan_top<<<1, 256, 0, stream>>>(bsum, boff, nb);
  k_scan_final<<<nb, 256, 0, stream>>>(deg, boff, row_start);
  k_scatter<<<1024, 256, 0, stream>>>(erow, ecol, row_start, fill, col_sorted);

  k_wt<<<(256 * 256 + 255) / 256, 256, 0, stream>>>(W0, Wt0, 256, 256);
  k_wt<<<(256 * 256 + 255) / 256, 256, 0, stream>>>(W1, Wt1, 256, 256);
  k_wt<<<(256 * 128 + 255) / 256, 256, 0, stream>>>(W2, Wt2, 256, 128);

  int mblocks = (N_NODES + 127) / 128;        // 391
  int agg_grid = (N_NODES * 64 + 255) / 256;  // 12500
  // layer 0
  k_gemm_bf16<256, false><<<mblocks, 512, 0, stream>>>(x, Wt0, nullptr, dis, hs);
  k_agg_bf16<<<agg_grid, 256, 0, stream>>>(hs, col_sorted, row_start, dis, b0, pre);
  k_bnstatsA<<<BNA_BLOCKS, 256, 0, stream>>>(pre, bnpart);
  k_bnstatsB<<<8, 512, 0, stream>>>(bnpart, bnpart2);
  k_bnfinal<<<1, 256, 0, stream>>>(bnpart2, g0, be0, ss0);
  // layer 1
  k_gemm_bf16<256, true><<<mblocks, 512, 0, stream>>>(pre, Wt1, ss0, dis, hs);
  k_agg_bf16<<<agg_grid, 256, 0, stream>>>(hs, col_sorted, row_start, dis, b1, pre);
  k_bnstatsA<<<BNA_BLOCKS, 256, 0, stream>>>(pre, bnpart);
  k_bnstatsB<<<8, 512, 0, stream>>>(bnpart, bnpart2);
  k_bnfinal<<<1, 256, 0, stream>>>(bnpart2, g1, be1, ss1);
  // layer 2 + fused log_softmax
  k_gemm_bf16<128, true><<<mblocks, 256, 0, stream>>>(pre, Wt2, ss1, dis, hs);
  k_agg_lsm_bf16<<<agg_grid, 256, 0, stream>>>(hs, col_sorted, row_start, dis, b2, out);
}

// Round 13
// 366.887 us; speedup vs baseline: 1.3062x; 1.0130x over previous
//
#include <hip/hip_runtime.h>

constexpr int N_NODES = 50000;
constexpr int N_EDGES = 800000;
constexpr float BN_EPS = 1e-5f;
constexpr int BNA_BLOCKS = 256;

typedef __attribute__((ext_vector_type(8))) short short8;
typedef __attribute__((ext_vector_type(4))) float f32x4;

__device__ __forceinline__ float bf2f(ushort u) {
  union { uint i; float f; } v;
  v.i = ((uint)u) << 16;
  return v.f;
}
__device__ __forceinline__ ushort f2bf(float f) {
  union { float f; uint i; } v;
  v.f = f;
  uint r = v.i + 0x7fff + ((v.i >> 16) & 1);  // RNE
  return (ushort)(r >> 16);
}

// ---------------- degree / normalization ----------------
__global__ void k_deg(const int* __restrict__ row, int* __restrict__ deg) {
  int i = blockIdx.x * blockDim.x + threadIdx.x;
  int stride = gridDim.x * blockDim.x;
  for (; i < N_EDGES; i += stride) atomicAdd(&deg[row[i]], 1);
}

__global__ void k_disqrt(const int* __restrict__ deg, float* __restrict__ dis) {
  int i = blockIdx.x * blockDim.x + threadIdx.x;
  if (i < N_NODES) dis[i] = rsqrtf((float)(deg[i] + 1));
}

// ---------------- CSR build: 3-phase scan + scatter ----------------
__global__ void k_scan_part(const int* __restrict__ deg, int* __restrict__ bsum) {
  __shared__ int s[256];
  int t = threadIdx.x, i = blockIdx.x * 256 + t;
  s[t] = (i < N_NODES) ? deg[i] : 0;
  __syncthreads();
  for (int off = 128; off > 0; off >>= 1) {
    if (t < off) s[t] += s[t + off];
    __syncthreads();
  }
  if (t == 0) bsum[blockIdx.x] = s[0];
}

__global__ void k_scan_top(const int* __restrict__ bsum, int* __restrict__ boff, int nb) {
  __shared__ int s[256];
  int t = threadIdx.x;
  int v = (t < nb) ? bsum[t] : 0;
  s[t] = v;
  __syncthreads();
  for (int off = 1; off < 256; off <<= 1) {
    int x = (t >= off) ? s[t - off] : 0;
    __syncthreads();
    s[t] += x;
    __syncthreads();
  }
  if (t < nb) boff[t] = s[t] - v;  // exclusive
}

__global__ void k_scan_final(const int* __restrict__ deg, const int* __restrict__ boff,
                             int* __restrict__ row_start) {
  __shared__ int s[256];
  int t = threadIdx.x, i = blockIdx.x * 256 + t;
  int v = (i < N_NODES) ? deg[i] : 0;
  s[t] = v;
  __syncthreads();
  for (int off = 1; off < 256; off <<= 1) {
    int x = (t >= off) ? s[t - off] : 0;
    __syncthreads();
    s[t] += x;
    __syncthreads();
  }
  if (i < N_NODES) row_start[i] = boff[blockIdx.x] + s[t] - v;
  if (i == 0) row_start[N_NODES] = N_EDGES;
}

__global__ void k_scatter(const int* __restrict__ row, const int* __restrict__ col,
                          const int* __restrict__ row_start, int* __restrict__ fill,
                          int* __restrict__ col_sorted) {
  int i = blockIdx.x * blockDim.x + threadIdx.x;
  int stride = gridDim.x * blockDim.x;
  for (; i < N_EDGES; i += stride) {
    int r = row[i];
    int pos = row_start[r] + atomicAdd(&fill[r], 1);
    col_sorted[pos] = col[i];
  }
}

// ---------------- W transpose to bf16: Wt[n][k] = bf16(W[k][n]) ----------------
__global__ void k_wt(const float* __restrict__ W, ushort* __restrict__ Wt, int K, int N) {
  int idx = blockIdx.x * 256 + threadIdx.x;
  if (idx >= K * N) return;
  int n = idx / K, k = idx % K;
  Wt[idx] = f2bf(W[(size_t)k * N + n]);
}

// ---------------- bf16 MFMA GEMM: hs = bf16( f(A) @ W * d_isqrt ) ----------------
// APPLY_BN: A is bf16 [N,256], f(A)=relu(A*scale+shift). else A fp32 [N,256], f=id.
// BM=128, BN=D, BK=32. D=256: 512 thr = 8 waves (2x4), A staged ONCE per row-tile.
template <int D, bool APPLY_BN>
__global__ __launch_bounds__(128 * (D / 64)) void k_gemm_bf16(const void* __restrict__ Av,
                                                              const ushort* __restrict__ Wt,
                                                              const float* __restrict__ ss,
                                                              const float* __restrict__ dis,
                                                              ushort* __restrict__ hs) {
  constexpr int THREADS = 128 * (D / 64);  // 512 (D=256) / 256 (D=128)
  constexpr int BM = 128, BK = 32, K = 256;
  constexpr int WC = D / 64;  // wave cols: 4 / 2
  constexpr int LDP = BK + 8;  // 40 bf16 (80B) stride: conflict-free b128 frags
  __shared__ ushort As[BM * LDP];
  __shared__ ushort Bs[D * LDP];
  const int tid = threadIdx.x;
  const int lane = tid & 63;
  const int wid = tid >> 6;
  const int wr = wid / WC, wc = wid % WC;
  const int rb = blockIdx.x * BM;

  f32x4 acc[4][4];
#pragma unroll
  for (int m = 0; m < 4; ++m)
#pragma unroll
    for (int n = 0; n < 4; ++n) acc[m][n] = (f32x4)(0.f);

  for (int kt = 0; kt < K; kt += BK) {
#pragma unroll
    for (int it = 0; it < 512 / THREADS; ++it) {
      int idx = tid + it * THREADS;
      int row = idx >> 2, kq = idx & 3;
      int gr = rb + row;
      if (gr >= N_NODES) gr = N_NODES - 1;
      float e[8];
      if constexpr (APPLY_BN) {
        const ushort* A = (const ushort*)Av;
        short8 v = *reinterpret_cast<const short8*>(&A[(size_t)gr * K + kt + kq * 8]);
#pragma unroll
        for (int q = 0; q < 8; ++q) {
          int k = kt + kq * 8 + q;
          e[q] = fmaxf(bf2f((ushort)v[q]) * ss[k] + ss[256 + k], 0.f);
        }
      } else {
        const float* A = (const float*)Av;
        const float4* src = reinterpret_cast<const float4*>(&A[(size_t)gr * K + kt + kq * 8]);
        float4 v0 = src[0], v1 = src[1];
        e[0] = v0.x; e[1] = v0.y; e[2] = v0.z; e[3] = v0.w;
        e[4] = v1.x; e[5] = v1.y; e[6] = v1.z; e[7] = v1.w;
      }
      short8 pk;
#pragma unroll
      for (int q = 0; q < 8; ++q) pk[q] = (short)f2bf(e[q]);
      *reinterpret_cast<short8*>(&As[row * LDP + kq * 8]) = pk;
    }
#pragma unroll
    for (int it = 0; it < D * 4 / THREADS; ++it) {
      int idx = tid + it * THREADS;
      int n = idx >> 2, kq = idx & 3;
      short8 v = *reinterpret_cast<const short8*>(&Wt[(size_t)n * K + kt + kq * 8]);
      *reinterpret_cast<short8*>(&Bs[n * LDP + kq * 8]) = v;
    }
    __syncthreads();

    const int rl = lane & 15;
    const int kb = (lane >> 4) * 8;
    short8 af[4], bfr[4];
#pragma unroll
    for (int f = 0; f < 4; ++f) {
      af[f] = *reinterpret_cast<short8*>(&As[(wr * 64 + f * 16 + rl) * LDP + kb]);
      bfr[f] = *reinterpret_cast<short8*>(&Bs[(wc * 64 + f * 16 + rl) * LDP + kb]);
    }
#pragma unroll
    for (int m = 0; m < 4; ++m)
#pragma unroll
      for (int n = 0; n < 4; ++n)
        acc[m][n] = __builtin_amdgcn_mfma_f32_16x16x32_bf16(af[m], bfr[n], acc[m][n], 0, 0, 0);
    __syncthreads();
  }

  const int cl = lane & 15;
  const int rq = lane >> 4;
#pragma unroll
  for (int m = 0; m < 4; ++m) {
    int rbase = rb + wr * 64 + m * 16 + rq * 4;
#pragma unroll
    for (int j = 0; j < 4; ++j) {
      int row = rbase + j;
      if (row >= N_NODES) continue;
      float di = dis[row];
#pragma unroll
      for (int n = 0; n < 4; ++n) {
        int col = wc * 64 + n * 16 + cl;
        hs[(size_t)row * D + col] = f2bf(acc[m][n][j] * di);
      }
    }
  }
}

// ---------------- aggregation: wave/node, 2 edges per 16B-lane instruction ---------
// D=256: row = 512B = 32 lanes x short8. half=lane>>5 takes even/odd edges;
// lane owns 8 cols; one shfl_xor(32) fold at the end. Tail weight-folded, step 2.
__global__ __launch_bounds__(256) void k_agg_bf16(const ushort* __restrict__ hs,
                                                  const int* __restrict__ cs,
                                                  const int* __restrict__ rs,
                                                  const float* __restrict__ dis,
                                                  const float* __restrict__ bias,
                                                  ushort* __restrict__ pre) {
  int gw = (blockIdx.x * 256 + threadIdx.x) >> 6;
  if (gw >= N_NODES) return;
  const int lane = threadIdx.x & 63;
  const int half = lane >> 5;
  const int c8 = lane & 31;
  const size_t coff = (size_t)c8 * 8;

  float a[8];
  short8 sv = *reinterpret_cast<const short8*>(&hs[(size_t)gw * 256 + coff]);
#pragma unroll
  for (int q = 0; q < 8; ++q) a[q] = half ? 0.f : bf2f((ushort)sv[q]);

  int s = rs[gw], e = rs[gw + 1];
  for (int base = s; base < e; base += 64) {
    int nav = min(64, e - base);
    int idx = (base + lane < e) ? cs[base + lane] : 0;
    int j = 0;
    for (; j + 8 <= nav; j += 8) {  // 8 edges: 4 dual-loads in flight
      short8 v[4];
#pragma unroll
      for (int u = 0; u < 4; ++u) {
        int c = __shfl(idx, j + 2 * u + half);
        v[u] = *reinterpret_cast<const short8*>(&hs[(size_t)((uint)c) * 256 + coff]);
      }
#pragma unroll
      for (int u = 0; u < 4; ++u)
#pragma unroll
        for (int q = 0; q < 8; ++q) a[q] += bf2f((ushort)v[u][q]);
    }
    for (; j < nav; j += 2) {  // tail: weight-folded dual-load
      int je = j + half;
      int c = __shfl(idx, je & 63);
      float w = (je < nav) ? 1.f : 0.f;
      short8 v = *reinterpret_cast<const short8*>(&hs[(size_t)((uint)c) * 256 + coff]);
#pragma unroll
      for (int q = 0; q < 8; ++q) a[q] = fmaf(w, bf2f((ushort)v[q]), a[q]);
    }
  }
#pragma unroll
  for (int q = 0; q < 8; ++q) a[q] += __shfl_xor(a[q], 32);

  if (half == 0) {
    float di = dis[gw];
    float4 b0 = *reinterpret_cast<const float4*>(&bias[c8 * 8]);
    float4 b1 = *reinterpret_cast<const float4*>(&bias[c8 * 8 + 4]);
    float bb[8] = {b0.x, b0.y, b0.z, b0.w, b1.x, b1.y, b1.z, b1.w};
    short8 o;
#pragma unroll
    for (int q = 0; q < 8; ++q) o[q] = (short)f2bf(a[q] * di + bb[q]);
    *reinterpret_cast<short8*>(&pre[(size_t)gw * 256 + coff]) = o;
  }
}

// layer-3 agg + log_softmax: D=128 row = 256B = 16 lanes x short8; 4 edges/instr.
__global__ __launch_bounds__(256) void k_agg_lsm_bf16(const ushort* __restrict__ hs,
                                                      const int* __restrict__ cs,
                                                      const int* __restrict__ rs,
                                                      const float* __restrict__ dis,
                                                      const float* __restrict__ bias,
                                                      float* __restrict__ out) {
  int gw = (blockIdx.x * 256 + threadIdx.x) >> 6;
  if (gw >= N_NODES) return;
  const int lane = threadIdx.x & 63;
  const int quad = lane >> 4;  // 0..3: edge slot
  const int c8 = lane & 15;
  const size_t coff = (size_t)c8 * 8;

  float a[8];
  short8 sv = *reinterpret_cast<const short8*>(&hs[(size_t)gw * 128 + coff]);
#pragma unroll
  for (int q = 0; q < 8; ++q) a[q] = quad ? 0.f : bf2f((ushort)sv[q]);

  int s = rs[gw], e = rs[gw + 1];
  for (int base = s; base < e; base += 64) {
    int nav = min(64, e - base);
    int idx = (base + lane < e) ? cs[base + lane] : 0;
    int j = 0;
    for (; j + 16 <= nav; j += 16) {  // 16 edges: 4 quad-loads in flight
      short8 v[4];
#pragma unroll
      for (int u = 0; u < 4; ++u) {
        int c = __shfl(idx, j + 4 * u + quad);
        v[u] = *reinterpret_cast<const short8*>(&hs[(size_t)((uint)c) * 128 + coff]);
      }
#pragma unroll
      for (int u = 0; u < 4; ++u)
#pragma unroll
        for (int q = 0; q < 8; ++q) a[q] += bf2f((ushort)v[u][q]);
    }
    for (; j < nav; j += 4) {  // tail: weight-folded quad-load
      int je = j + quad;
      int c = __shfl(idx, je & 63);
      float w = (je < nav) ? 1.f : 0.f;
      short8 v = *reinterpret_cast<const short8*>(&hs[(size_t)((uint)c) * 128 + coff]);
#pragma unroll
      for (int q = 0; q < 8; ++q) a[q] = fmaf(w, bf2f((ushort)v[q]), a[q]);
    }
  }
#pragma unroll
  for (int q = 0; q < 8; ++q) {
    a[q] += __shfl_xor(a[q], 16);
    a[q] += __shfl_xor(a[q], 32);
  }

  float di = dis[gw];
  float4 b0 = *reinterpret_cast<const float4*>(&bias[c8 * 8]);
  float4 b1 = *reinterpret_cast<const float4*>(&bias[c8 * 8 + 4]);
  float bb[8] = {b0.x, b0.y, b0.z, b0.w, b1.x, b1.y, b1.z, b1.w};
  float vv[8];
  float m = -1e30f;
#pragma unroll
  for (int q = 0; q < 8; ++q) {
    vv[q] = a[q] * di + bb[q];
    m = fmaxf(m, vv[q]);
  }
#pragma unroll
  for (int o = 1; o < 16; o <<= 1) m = fmaxf(m, __shfl_xor(m, o));
  float sum = 0.f;
#pragma unroll
  for (int q = 0; q < 8; ++q) sum += __expf(vv[q] - m);
#pragma unroll
  for (int o = 1; o < 16; o <<= 1) sum += __shfl_xor(sum, o);
  float ls = m + logf(sum);
  if (quad == 0) {
    float4 o0 = {vv[0] - ls, vv[1] - ls, vv[2] - ls, vv[3] - ls};
    float4 o1 = {vv[4] - ls, vv[5] - ls, vv[6] - ls, vv[7] - ls};
    *reinterpret_cast<float4*>(&out[(size_t)gw * 128 + coff]) = o0;
    *reinterpret_cast<float4*>(&out[(size_t)gw * 128 + coff + 4]) = o1;
  }
}

// ---------------- batchnorm stats: three-phase, atomic-free ----------------
__global__ __launch_bounds__(256) void k_bnstatsA(const ushort* __restrict__ pre,
                                                  float* __restrict__ partial) {
  int t = threadIdx.x;
  int rsub = t >> 7;
  int cp = (t & 127) * 2;
  float s0 = 0.f, s1 = 0.f, q0 = 0.f, q1 = 0.f;
  for (int r = blockIdx.x * 2 + rsub; r < N_NODES; r += BNA_BLOCKS * 2) {
    ushort2 v = *reinterpret_cast<const ushort2*>(&pre[(size_t)r * 256 + cp]);
    float f0 = bf2f(v.x), f1 = bf2f(v.y);
    s0 += f0;
    q0 += f0 * f0;
    s1 += f1;
    q1 += f1 * f1;
  }
  __shared__ float lsum[256], lsq[256];
  if (rsub) {
    lsum[cp] = s0;
    lsum[cp + 1] = s1;
    lsq[cp] = q0;
    lsq[cp + 1] = q1;
  }
  __syncthreads();
  if (!rsub) {
    float* p = &partial[(size_t)blockIdx.x * 512];
    p[cp] = s0 + lsum[cp];
    p[cp + 1] = s1 + lsum[cp + 1];
    p[256 + cp] = q0 + lsq[cp];
    p[256 + cp + 1] = q1 + lsq[cp + 1];
  }
}

__global__ __launch_bounds__(512) void k_bnstatsB(const float* __restrict__ partial,
                                                  float* __restrict__ p2) {
  int t = threadIdx.x, b = blockIdx.x;
  float a = 0.f;
#pragma unroll 8
  for (int r = 0; r < BNA_BLOCKS / 8; ++r)
    a += partial[(size_t)(b * (BNA_BLOCKS / 8) + r) * 512 + t];
  p2[(size_t)b * 512 + t] = a;
}

__global__ void k_bnfinal(const float* __restrict__ p2, const float* __restrict__ gamma,
                          const float* __restrict__ beta, float* __restrict__ ss) {
  int t = threadIdx.x;
  float sum = 0.f, sq = 0.f;
#pragma unroll
  for (int b = 0; b < 8; ++b) {
    sum += p2[(size_t)b * 512 + t];
    sq += p2[(size_t)b * 512 + 256 + t];
  }
  float mu = sum * (1.f / N_NODES);
  float var = sq * (1.f / N_NODES) - mu * mu;
  float sc = gamma[t] * rsqrtf(var + BN_EPS);
  ss[t] = sc;
  ss[256 + t] = beta[t] - mu * sc;
}

// ---------------- launcher ----------------
extern "C" void kernel_launch(void* const* d_in, const int* in_sizes, int n_in,
                              void* d_out, int out_size, void* d_ws, size_t ws_size,
                              hipStream_t stream) {
  const float* x = (const float*)d_in[0];
  const int* erow = (const int*)d_in[1];
  const int* ecol = erow + N_EDGES;
  const float* W0 = (const float*)d_in[2];
  const float* b0 = (const float*)d_in[3];
  const float* W1 = (const float*)d_in[4];
  const float* b1 = (const float*)d_in[5];
  const float* W2 = (const float*)d_in[6];
  const float* b2 = (const float*)d_in[7];
  const float* g0 = (const float*)d_in[8];
  const float* be0 = (const float*)d_in[9];
  const float* g1 = (const float*)d_in[10];
  const float* be1 = (const float*)d_in[11];
  float* out = (float*)d_out;

  char* ws = (char*)d_ws;
  size_t off = 0;
  auto take = [&](size_t bytes) {
    char* p = ws + off;
    off = (off + bytes + 255) & ~(size_t)255;
    return p;
  };
  int* deg = (int*)take(N_NODES * 4);
  int* fill = (int*)take(N_NODES * 4);
  size_t zero_bytes = off;  // deg+fill must start at 0 each call
  float* bnpart = (float*)take((size_t)BNA_BLOCKS * 512 * 4);
  float* bnpart2 = (float*)take(8 * 512 * 4);
  float* dis = (float*)take(N_NODES * 4);
  int* row_start = (int*)take((N_NODES + 1) * 4);
  int* bsum = (int*)take(256 * 4);
  int* boff = (int*)take(256 * 4);
  float* ss0 = (float*)take(512 * 4);
  float* ss1 = (float*)take(512 * 4);
  ushort* Wt0 = (ushort*)take(256 * 256 * 2);
  ushort* Wt1 = (ushort*)take(256 * 256 * 2);
  ushort* Wt2 = (ushort*)take(256 * 128 * 2);
  int* col_sorted = (int*)take((size_t)N_EDGES * 4);
  ushort* hs = (ushort*)take((size_t)N_NODES * 256 * 2);
  ushort* pre = (ushort*)take((size_t)N_NODES * 256 * 2);
  if (off > ws_size) return;

  hipMemsetAsync(d_ws, 0, zero_bytes, stream);

  k_deg<<<1024, 256, 0, stream>>>(erow, deg);
  k_disqrt<<<(N_NODES + 255) / 256, 256, 0, stream>>>(deg, dis);
  int nb = (N_NODES + 255) / 256;  // 196
  k_scan_part<<<nb, 256, 0, stream>>>(deg, bsum);
  k_scan_top<<<1, 256, 0, stream>>>(bsum, boff, nb);
  k_scan_final<<<nb, 256, 0, stream>>>(deg, boff, row_start);
  k_scatter<<<1024, 256, 0, stream>>>(erow, ecol, row_start, fill, col_sorted);

  k_wt<<<(256 * 256 + 255) / 256, 256, 0, stream>>>(W0, Wt0, 256, 256);
  k_wt<<<(256 * 256 + 255) / 256, 256, 0, stream>>>(W1, Wt1, 256, 256);
  k_wt<<<(256 * 128 + 255) / 256, 256, 0, stream>>>(W2, Wt2, 256, 128);

  int mblocks = (N_NODES + 127) / 128;        // 391
  int agg_grid = (N_NODES * 64 + 255) / 256;  // 12500
  // layer 0
  k_gemm_bf16<256, false><<<mblocks, 512, 0, stream>>>(x, Wt0, nullptr, dis, hs);
  k_agg_bf16<<<agg_grid, 256, 0, stream>>>(hs, col_sorted, row_start, dis, b0, pre);
  k_bnstatsA<<<BNA_BLOCKS, 256, 0, stream>>>(pre, bnpart);
  k_bnstatsB<<<8, 512, 0, stream>>>(bnpart, bnpart2);
  k_bnfinal<<<1, 256, 0, stream>>>(bnpart2, g0, be0, ss0);
  // layer 1
  k_gemm_bf16<256, true><<<mblocks, 512, 0, stream>>>(pre, Wt1, ss0, dis, hs);
  k_agg_bf16<<<agg_grid, 256, 0, stream>>>(hs, col_sorted, row_start, dis, b1, pre);
  k_bnstatsA<<<BNA_BLOCKS, 256, 0, stream>>>(pre, bnpart);
  k_bnstatsB<<<8, 512, 0, stream>>>(bnpart, bnpart2);
  k_bnfinal<<<1, 256, 0, stream>>>(bnpart2, g1, be1, ss1);
  // layer 2 + fused log_softmax
  k_gemm_bf16<128, true><<<mblocks, 256, 0, stream>>>(pre, Wt2, ss1, dis, hs);
  k_agg_lsm_bf16<<<agg_grid, 256, 0, stream>>>(hs, col_sorted, row_start, dis, b2, out);
}

// Round 14
// 317.921 us; speedup vs baseline: 1.5074x; 1.1540x over previous
//
#include <hip/hip_runtime.h>

constexpr int N_NODES = 50000;
constexpr int N_EDGES = 800000;
constexpr float BN_EPS = 1e-5f;
constexpr int BNA_BLOCKS = 256;

typedef __attribute__((ext_vector_type(8))) short short8;
typedef __attribute__((ext_vector_type(4))) float f32x4;
typedef __attribute__((ext_vector_type(2))) float f32x2;

__device__ __forceinline__ float bf2f(ushort u) {
  union { uint i; float f; } v;
  v.i = ((uint)u) << 16;
  return v.f;
}
__device__ __forceinline__ ushort f2bf(float f) {
  union { float f; uint i; } v;
  v.f = f;
  uint r = v.i + 0x7fff + ((v.i >> 16) & 1);  // RNE
  return (ushort)(r >> 16);
}
__device__ __forceinline__ uchar f2fp8(float v) {
  int r = __builtin_amdgcn_cvt_pk_fp8_f32(v, 0.f, 0, false);
  return (uchar)(r & 0xff);
}
__device__ __forceinline__ void dec4(uint w, float* o) {
  f32x2 lo = __builtin_amdgcn_cvt_pk_f32_fp8(w, false);
  f32x2 hi = __builtin_amdgcn_cvt_pk_f32_fp8(w, true);
  o[0] = lo.x;
  o[1] = lo.y;
  o[2] = hi.x;
  o[3] = hi.y;
}

// ---------------- degree / normalization ----------------
__global__ void k_deg(const int* __restrict__ row, int* __restrict__ deg) {
  int i = blockIdx.x * blockDim.x + threadIdx.x;
  int stride = gridDim.x * blockDim.x;
  for (; i < N_EDGES; i += stride) atomicAdd(&deg[row[i]], 1);
}

__global__ void k_disqrt(const int* __restrict__ deg, float* __restrict__ dis) {
  int i = blockIdx.x * blockDim.x + threadIdx.x;
  if (i < N_NODES) dis[i] = rsqrtf((float)(deg[i] + 1));
}

// ---------------- CSR build: 3-phase scan + scatter ----------------
__global__ void k_scan_part(const int* __restrict__ deg, int* __restrict__ bsum) {
  __shared__ int s[256];
  int t = threadIdx.x, i = blockIdx.x * 256 + t;
  s[t] = (i < N_NODES) ? deg[i] : 0;
  __syncthreads();
  for (int off = 128; off > 0; off >>= 1) {
    if (t < off) s[t] += s[t + off];
    __syncthreads();
  }
  if (t == 0) bsum[blockIdx.x] = s[0];
}

__global__ void k_scan_top(const int* __restrict__ bsum, int* __restrict__ boff, int nb) {
  __shared__ int s[256];
  int t = threadIdx.x;
  int v = (t < nb) ? bsum[t] : 0;
  s[t] = v;
  __syncthreads();
  for (int off = 1; off < 256; off <<= 1) {
    int x = (t >= off) ? s[t - off] : 0;
    __syncthreads();
    s[t] += x;
    __syncthreads();
  }
  if (t < nb) boff[t] = s[t] - v;  // exclusive
}

__global__ void k_scan_final(const int* __restrict__ deg, const int* __restrict__ boff,
                             int* __restrict__ row_start) {
  __shared__ int s[256];
  int t = threadIdx.x, i = blockIdx.x * 256 + t;
  int v = (i < N_NODES) ? deg[i] : 0;
  s[t] = v;
  __syncthreads();
  for (int off = 1; off < 256; off <<= 1) {
    int x = (t >= off) ? s[t - off] : 0;
    __syncthreads();
    s[t] += x;
    __syncthreads();
  }
  if (i < N_NODES) row_start[i] = boff[blockIdx.x] + s[t] - v;
  if (i == 0) row_start[N_NODES] = N_EDGES;
}

__global__ void k_scatter(const int* __restrict__ row, const int* __restrict__ col,
                          const int* __restrict__ row_start, int* __restrict__ fill,
                          int* __restrict__ col_sorted) {
  int i = blockIdx.x * blockDim.x + threadIdx.x;
  int stride = gridDim.x * blockDim.x;
  for (; i < N_EDGES; i += stride) {
    int r = row[i];
    int pos = row_start[r] + atomicAdd(&fill[r], 1);
    col_sorted[pos] = col[i];
  }
}

// ---------------- W transpose to bf16: Wt[n][k] = bf16(W[k][n]) ----------------
__global__ void k_wt(const float* __restrict__ W, ushort* __restrict__ Wt, int K, int N) {
  int idx = blockIdx.x * 256 + threadIdx.x;
  if (idx >= K * N) return;
  int n = idx / K, k = idx % K;
  Wt[idx] = f2bf(W[(size_t)k * N + n]);
}

// ---------------- bf16 MFMA GEMM: hs = cvt( f(A) @ W * d_isqrt ) ----------------
// APPLY_BN: A is bf16 [N,256], f(A)=relu(A*scale+shift). else A fp32 [N,256], f=id.
// OUT_FP8: hs stored fp8 e4m3 [N][D] (gather operand); else bf16.
template <int D, bool APPLY_BN, bool OUT_FP8>
__global__ __launch_bounds__(128 * (D / 64)) void k_gemm_bf16(const void* __restrict__ Av,
                                                              const ushort* __restrict__ Wt,
                                                              const float* __restrict__ ss,
                                                              const float* __restrict__ dis,
                                                              void* __restrict__ hsv) {
  constexpr int THREADS = 128 * (D / 64);  // 512 (D=256) / 256 (D=128)
  constexpr int BM = 128, BK = 32, K = 256;
  constexpr int WC = D / 64;
  constexpr int LDP = BK + 8;
  __shared__ ushort As[BM * LDP];
  __shared__ ushort Bs[D * LDP];
  const int tid = threadIdx.x;
  const int lane = tid & 63;
  const int wid = tid >> 6;
  const int wr = wid / WC, wc = wid % WC;
  const int rb = blockIdx.x * BM;

  f32x4 acc[4][4];
#pragma unroll
  for (int m = 0; m < 4; ++m)
#pragma unroll
    for (int n = 0; n < 4; ++n) acc[m][n] = (f32x4)(0.f);

  for (int kt = 0; kt < K; kt += BK) {
#pragma unroll
    for (int it = 0; it < 512 / THREADS; ++it) {
      int idx = tid + it * THREADS;
      int row = idx >> 2, kq = idx & 3;
      int gr = rb + row;
      if (gr >= N_NODES) gr = N_NODES - 1;
      float e[8];
      if constexpr (APPLY_BN) {
        const ushort* A = (const ushort*)Av;
        short8 v = *reinterpret_cast<const short8*>(&A[(size_t)gr * K + kt + kq * 8]);
#pragma unroll
        for (int q = 0; q < 8; ++q) {
          int k = kt + kq * 8 + q;
          e[q] = fmaxf(bf2f((ushort)v[q]) * ss[k] + ss[256 + k], 0.f);
        }
      } else {
        const float* A = (const float*)Av;
        const float4* src = reinterpret_cast<const float4*>(&A[(size_t)gr * K + kt + kq * 8]);
        float4 v0 = src[0], v1 = src[1];
        e[0] = v0.x; e[1] = v0.y; e[2] = v0.z; e[3] = v0.w;
        e[4] = v1.x; e[5] = v1.y; e[6] = v1.z; e[7] = v1.w;
      }
      short8 pk;
#pragma unroll
      for (int q = 0; q < 8; ++q) pk[q] = (short)f2bf(e[q]);
      *reinterpret_cast<short8*>(&As[row * LDP + kq * 8]) = pk;
    }
#pragma unroll
    for (int it = 0; it < D * 4 / THREADS; ++it) {
      int idx = tid + it * THREADS;
      int n = idx >> 2, kq = idx & 3;
      short8 v = *reinterpret_cast<const short8*>(&Wt[(size_t)n * K + kt + kq * 8]);
      *reinterpret_cast<short8*>(&Bs[n * LDP + kq * 8]) = v;
    }
    __syncthreads();

    const int rl = lane & 15;
    const int kb = (lane >> 4) * 8;
    short8 af[4], bfr[4];
#pragma unroll
    for (int f = 0; f < 4; ++f) {
      af[f] = *reinterpret_cast<short8*>(&As[(wr * 64 + f * 16 + rl) * LDP + kb]);
      bfr[f] = *reinterpret_cast<short8*>(&Bs[(wc * 64 + f * 16 + rl) * LDP + kb]);
    }
#pragma unroll
    for (int m = 0; m < 4; ++m)
#pragma unroll
      for (int n = 0; n < 4; ++n)
        acc[m][n] = __builtin_amdgcn_mfma_f32_16x16x32_bf16(af[m], bfr[n], acc[m][n], 0, 0, 0);
    __syncthreads();
  }

  const int cl = lane & 15;
  const int rq = lane >> 4;
#pragma unroll
  for (int m = 0; m < 4; ++m) {
    int rbase = rb + wr * 64 + m * 16 + rq * 4;
#pragma unroll
    for (int j = 0; j < 4; ++j) {
      int row = rbase + j;
      if (row >= N_NODES) continue;
      float di = dis[row];
#pragma unroll
      for (int n = 0; n < 4; ++n) {
        int col = wc * 64 + n * 16 + cl;
        if constexpr (OUT_FP8) {
          ((uchar*)hsv)[(size_t)row * D + col] = f2fp8(acc[m][n][j] * di);
        } else {
          ((ushort*)hsv)[(size_t)row * D + col] = f2bf(acc[m][n][j] * di);
        }
      }
    }
  }
}

// ---------------- fp8 aggregation: pre = bf16(dis*(self+sum_nbr)+b) ----------------
// D=256 fp8 row = 256B = 16 lanes x 16B (16 cols/lane). quad=lane>>4: 4 edge slots,
// 16 edges in flight per unrolled body. Decode via packed v_cvt_pk_f32_fp8.
__global__ __launch_bounds__(256) void k_agg_fp8(const uchar* __restrict__ hs8,
                                                 const int* __restrict__ cs,
                                                 const int* __restrict__ rs,
                                                 const float* __restrict__ dis,
                                                 const float* __restrict__ bias,
                                                 ushort* __restrict__ pre) {
  int gw = (blockIdx.x * 256 + threadIdx.x) >> 6;
  if (gw >= N_NODES) return;
  const int lane = threadIdx.x & 63;
  const int quad = lane >> 4;
  const int c16 = lane & 15;
  const size_t coff = (size_t)c16 * 16;

  float a[16];
  {
    uint4 sv = *reinterpret_cast<const uint4*>(&hs8[(size_t)gw * 256 + coff]);
    float tmp[16];
    dec4(sv.x, tmp);
    dec4(sv.y, tmp + 4);
    dec4(sv.z, tmp + 8);
    dec4(sv.w, tmp + 12);
#pragma unroll
    for (int q = 0; q < 16; ++q) a[q] = quad ? 0.f : tmp[q];
  }

  int s = rs[gw], e = rs[gw + 1];
  for (int base = s; base < e; base += 64) {
    int nav = min(64, e - base);
    int idx = (base + lane < e) ? cs[base + lane] : 0;
    int j = 0;
    for (; j + 16 <= nav; j += 16) {  // 16 edges: 4 loads in flight
      uint4 v[4];
#pragma unroll
      for (int u = 0; u < 4; ++u) {
        int c = __shfl(idx, j + 4 * u + quad);
        v[u] = *reinterpret_cast<const uint4*>(&hs8[(size_t)((uint)c) * 256 + coff]);
      }
#pragma unroll
      for (int u = 0; u < 4; ++u) {
        float tmp[16];
        dec4(v[u].x, tmp);
        dec4(v[u].y, tmp + 4);
        dec4(v[u].z, tmp + 8);
        dec4(v[u].w, tmp + 12);
#pragma unroll
        for (int q = 0; q < 16; ++q) a[q] += tmp[q];
      }
    }
    for (; j < nav; j += 4) {  // tail: weight-folded quad-load
      int je = j + quad;
      int c = __shfl(idx, je & 63);
      float w = (je < nav) ? 1.f : 0.f;
      uint4 v = *reinterpret_cast<const uint4*>(&hs8[(size_t)((uint)c) * 256 + coff]);
      float tmp[16];
      dec4(v.x, tmp);
      dec4(v.y, tmp + 4);
      dec4(v.z, tmp + 8);
      dec4(v.w, tmp + 12);
#pragma unroll
      for (int q = 0; q < 16; ++q) a[q] = fmaf(w, tmp[q], a[q]);
    }
  }
#pragma unroll
  for (int q = 0; q < 16; ++q) {
    a[q] += __shfl_xor(a[q], 16);
    a[q] += __shfl_xor(a[q], 32);
  }

  if (quad == 0) {
    float di = dis[gw];
    float bb[16];
#pragma unroll
    for (int p = 0; p < 4; ++p) {
      float4 b = *reinterpret_cast<const float4*>(&bias[coff + p * 4]);
      bb[p * 4] = b.x;
      bb[p * 4 + 1] = b.y;
      bb[p * 4 + 2] = b.z;
      bb[p * 4 + 3] = b.w;
    }
    short8 o0, o1;
#pragma unroll
    for (int q = 0; q < 8; ++q) {
      o0[q] = (short)f2bf(a[q] * di + bb[q]);
      o1[q] = (short)f2bf(a[8 + q] * di + bb[8 + q]);
    }
    *reinterpret_cast<short8*>(&pre[(size_t)gw * 256 + coff]) = o0;
    *reinterpret_cast<short8*>(&pre[(size_t)gw * 256 + coff + 8]) = o1;
  }
}

// layer-3 agg + log_softmax: D=128 bf16 row = 256B = 16 lanes x short8; 4 edges/instr.
__global__ __launch_bounds__(256) void k_agg_lsm_bf16(const ushort* __restrict__ hs,
                                                      const int* __restrict__ cs,
                                                      const int* __restrict__ rs,
                                                      const float* __restrict__ dis,
                                                      const float* __restrict__ bias,
                                                      float* __restrict__ out) {
  int gw = (blockIdx.x * 256 + threadIdx.x) >> 6;
  if (gw >= N_NODES) return;
  const int lane = threadIdx.x & 63;
  const int quad = lane >> 4;
  const int c8 = lane & 15;
  const size_t coff = (size_t)c8 * 8;

  float a[8];
  short8 sv = *reinterpret_cast<const short8*>(&hs[(size_t)gw * 128 + coff]);
#pragma unroll
  for (int q = 0; q < 8; ++q) a[q] = quad ? 0.f : bf2f((ushort)sv[q]);

  int s = rs[gw], e = rs[gw + 1];
  for (int base = s; base < e; base += 64) {
    int nav = min(64, e - base);
    int idx = (base + lane < e) ? cs[base + lane] : 0;
    int j = 0;
    for (; j + 16 <= nav; j += 16) {
      short8 v[4];
#pragma unroll
      for (int u = 0; u < 4; ++u) {
        int c = __shfl(idx, j + 4 * u + quad);
        v[u] = *reinterpret_cast<const short8*>(&hs[(size_t)((uint)c) * 128 + coff]);
      }
#pragma unroll
      for (int u = 0; u < 4; ++u)
#pragma unroll
        for (int q = 0; q < 8; ++q) a[q] += bf2f((ushort)v[u][q]);
    }
    for (; j < nav; j += 4) {
      int je = j + quad;
      int c = __shfl(idx, je & 63);
      float w = (je < nav) ? 1.f : 0.f;
      short8 v = *reinterpret_cast<const short8*>(&hs[(size_t)((uint)c) * 128 + coff]);
#pragma unroll
      for (int q = 0; q < 8; ++q) a[q] = fmaf(w, bf2f((ushort)v[q]), a[q]);
    }
  }
#pragma unroll
  for (int q = 0; q < 8; ++q) {
    a[q] += __shfl_xor(a[q], 16);
    a[q] += __shfl_xor(a[q], 32);
  }

  float di = dis[gw];
  float4 b0 = *reinterpret_cast<const float4*>(&bias[c8 * 8]);
  float4 b1 = *reinterpret_cast<const float4*>(&bias[c8 * 8 + 4]);
  float bb[8] = {b0.x, b0.y, b0.z, b0.w, b1.x, b1.y, b1.z, b1.w};
  float vv[8];
  float m = -1e30f;
#pragma unroll
  for (int q = 0; q < 8; ++q) {
    vv[q] = a[q] * di + bb[q];
    m = fmaxf(m, vv[q]);
  }
#pragma unroll
  for (int o = 1; o < 16; o <<= 1) m = fmaxf(m, __shfl_xor(m, o));
  float sum = 0.f;
#pragma unroll
  for (int q = 0; q < 8; ++q) sum += __expf(vv[q] - m);
#pragma unroll
  for (int o = 1; o < 16; o <<= 1) sum += __shfl_xor(sum, o);
  float ls = m + logf(sum);
  if (quad == 0) {
    float4 o0 = {vv[0] - ls, vv[1] - ls, vv[2] - ls, vv[3] - ls};
    float4 o1 = {vv[4] - ls, vv[5] - ls, vv[6] - ls, vv[7] - ls};
    *reinterpret_cast<float4*>(&out[(size_t)gw * 128 + coff]) = o0;
    *reinterpret_cast<float4*>(&out[(size_t)gw * 128 + coff + 4]) = o1;
  }
}

// ---------------- batchnorm stats: three-phase, atomic-free ----------------
__global__ __launch_bounds__(256) void k_bnstatsA(const ushort* __restrict__ pre,
                                                  float* __restrict__ partial) {
  int t = threadIdx.x;
  int rsub = t >> 7;
  int cp = (t & 127) * 2;
  float s0 = 0.f, s1 = 0.f, q0 = 0.f, q1 = 0.f;
  for (int r = blockIdx.x * 2 + rsub; r < N_NODES; r += BNA_BLOCKS * 2) {
    ushort2 v = *reinterpret_cast<const ushort2*>(&pre[(size_t)r * 256 + cp]);
    float f0 = bf2f(v.x), f1 = bf2f(v.y);
    s0 += f0;
    q0 += f0 * f0;
    s1 += f1;
    q1 += f1 * f1;
  }
  __shared__ float lsum[256], lsq[256];
  if (rsub) {
    lsum[cp] = s0;
    lsum[cp + 1] = s1;
    lsq[cp] = q0;
    lsq[cp + 1] = q1;
  }
  __syncthreads();
  if (!rsub) {
    float* p = &partial[(size_t)blockIdx.x * 512];
    p[cp] = s0 + lsum[cp];
    p[cp + 1] = s1 + lsum[cp + 1];
    p[256 + cp] = q0 + lsq[cp];
    p[256 + cp + 1] = q1 + lsq[cp + 1];
  }
}

__global__ __launch_bounds__(512) void k_bnstatsB(const float* __restrict__ partial,
                                                  float* __restrict__ p2) {
  int t = threadIdx.x, b = blockIdx.x;
  float a = 0.f;
#pragma unroll 8
  for (int r = 0; r < BNA_BLOCKS / 8; ++r)
    a += partial[(size_t)(b * (BNA_BLOCKS / 8) + r) * 512 + t];
  p2[(size_t)b * 512 + t] = a;
}

__global__ void k_bnfinal(const float* __restrict__ p2, const float* __restrict__ gamma,
                          const float* __restrict__ beta, float* __restrict__ ss) {
  int t = threadIdx.x;
  float sum = 0.f, sq = 0.f;
#pragma unroll
  for (int b = 0; b < 8; ++b) {
    sum += p2[(size_t)b * 512 + t];
    sq += p2[(size_t)b * 512 + 256 + t];
  }
  float mu = sum * (1.f / N_NODES);
  float var = sq * (1.f / N_NODES) - mu * mu;
  float sc = gamma[t] * rsqrtf(var + BN_EPS);
  ss[t] = sc;
  ss[256 + t] = beta[t] - mu * sc;
}

// ---------------- launcher ----------------
extern "C" void kernel_launch(void* const* d_in, const int* in_sizes, int n_in,
                              void* d_out, int out_size, void* d_ws, size_t ws_size,
                              hipStream_t stream) {
  const float* x = (const float*)d_in[0];
  const int* erow = (const int*)d_in[1];
  const int* ecol = erow + N_EDGES;
  const float* W0 = (const float*)d_in[2];
  const float* b0 = (const float*)d_in[3];
  const float* W1 = (const float*)d_in[4];
  const float* b1 = (const float*)d_in[5];
  const float* W2 = (const float*)d_in[6];
  const float* b2 = (const float*)d_in[7];
  const float* g0 = (const float*)d_in[8];
  const float* be0 = (const float*)d_in[9];
  const float* g1 = (const float*)d_in[10];
  const float* be1 = (const float*)d_in[11];
  float* out = (float*)d_out;

  char* ws = (char*)d_ws;
  size_t off = 0;
  auto take = [&](size_t bytes) {
    char* p = ws + off;
    off = (off + bytes + 255) & ~(size_t)255;
    return p;
  };
  int* deg = (int*)take(N_NODES * 4);
  int* fill = (int*)take(N_NODES * 4);
  size_t zero_bytes = off;  // deg+fill must start at 0 each call
  float* bnpart = (float*)take((size_t)BNA_BLOCKS * 512 * 4);
  float* bnpart2 = (float*)take(8 * 512 * 4);
  float* dis = (float*)take(N_NODES * 4);
  int* row_start = (int*)take((N_NODES + 1) * 4);
  int* bsum = (int*)take(256 * 4);
  int* boff = (int*)take(256 * 4);
  float* ss0 = (float*)take(512 * 4);
  float* ss1 = (float*)take(512 * 4);
  ushort* Wt0 = (ushort*)take(256 * 256 * 2);
  ushort* Wt1 = (ushort*)take(256 * 256 * 2);
  ushort* Wt2 = (ushort*)take(256 * 128 * 2);
  int* col_sorted = (int*)take((size_t)N_EDGES * 4);
  uchar* hs8 = (uchar*)take((size_t)N_NODES * 256);        // fp8 gather operand (L0/L1)
  ushort* hs = (ushort*)take((size_t)N_NODES * 128 * 2);   // bf16 (L2)
  ushort* pre = (ushort*)take((size_t)N_NODES * 256 * 2);  // bf16
  if (off > ws_size) return;

  hipMemsetAsync(d_ws, 0, zero_bytes, stream);

  k_deg<<<1024, 256, 0, stream>>>(erow, deg);
  k_disqrt<<<(N_NODES + 255) / 256, 256, 0, stream>>>(deg, dis);
  int nb = (N_NODES + 255) / 256;  // 196
  k_scan_part<<<nb, 256, 0, stream>>>(deg, bsum);
  k_scan_top<<<1, 256, 0, stream>>>(bsum, boff, nb);
  k_scan_final<<<nb, 256, 0, stream>>>(deg, boff, row_start);
  k_scatter<<<1024, 256, 0, stream>>>(erow, ecol, row_start, fill, col_sorted);

  k_wt<<<(256 * 256 + 255) / 256, 256, 0, stream>>>(W0, Wt0, 256, 256);
  k_wt<<<(256 * 256 + 255) / 256, 256, 0, stream>>>(W1, Wt1, 256, 256);
  k_wt<<<(256 * 128 + 255) / 256, 256, 0, stream>>>(W2, Wt2, 256, 128);

  int mblocks = (N_NODES + 127) / 128;        // 391
  int agg_grid = (N_NODES * 64 + 255) / 256;  // 12500
  // layer 0 (hs fp8)
  k_gemm_bf16<256, false, true><<<mblocks, 512, 0, stream>>>(x, Wt0, nullptr, dis, hs8);
  k_agg_fp8<<<agg_grid, 256, 0, stream>>>(hs8, col_sorted, row_start, dis, b0, pre);
  k_bnstatsA<<<BNA_BLOCKS, 256, 0, stream>>>(pre, bnpart);
  k_bnstatsB<<<8, 512, 0, stream>>>(bnpart, bnpart2);
  k_bnfinal<<<1, 256, 0, stream>>>(bnpart2, g0, be0, ss0);
  // layer 1 (hs fp8)
  k_gemm_bf16<256, true, true><<<mblocks, 512, 0, stream>>>(pre, Wt1, ss0, dis, hs8);
  k_agg_fp8<<<agg_grid, 256, 0, stream>>>(hs8, col_sorted, row_start, dis, b1, pre);
  k_bnstatsA<<<BNA_BLOCKS, 256, 0, stream>>>(pre, bnpart);
  k_bnstatsB<<<8, 512, 0, stream>>>(bnpart, bnpart2);
  k_bnfinal<<<1, 256, 0, stream>>>(bnpart2, g1, be1, ss1);
  // layer 2 (bf16) + fused log_softmax
  k_gemm_bf16<128, true, false><<<mblocks, 256, 0, stream>>>(pre, Wt2, ss1, dis, hs);
  k_agg_lsm_bf16<<<agg_grid, 256, 0, stream>>>(hs, col_sorted, row_start, dis, b2, out);
}

// Round 15
// 316.950 us; speedup vs baseline: 1.5120x; 1.0031x over previous
//
#include <hip/hip_runtime.h>

constexpr int N_NODES = 50000;
constexpr int N_EDGES = 800000;
constexpr float BN_EPS = 1e-5f;
constexpr int BNA_BLOCKS = 256;
constexpr int ROWS_PER_GROUP = (N_NODES + 7) / 8;  // 6250

typedef __attribute__((ext_vector_type(8))) short short8;
typedef __attribute__((ext_vector_type(4))) float f32x4;
typedef __attribute__((ext_vector_type(2))) float f32x2;

__device__ __forceinline__ float bf2f(ushort u) {
  union { uint i; float f; } v;
  v.i = ((uint)u) << 16;
  return v.f;
}
__device__ __forceinline__ ushort f2bf(float f) {
  union { float f; uint i; } v;
  v.f = f;
  uint r = v.i + 0x7fff + ((v.i >> 16) & 1);  // RNE
  return (ushort)(r >> 16);
}
__device__ __forceinline__ uchar f2fp8(float v) {
  int r = __builtin_amdgcn_cvt_pk_fp8_f32(v, 0.f, 0, false);
  return (uchar)(r & 0xff);
}
__device__ __forceinline__ void dec4(uint w, float* o) {
  f32x2 lo = __builtin_amdgcn_cvt_pk_f32_fp8(w, false);
  f32x2 hi = __builtin_amdgcn_cvt_pk_f32_fp8(w, true);
  o[0] = lo.x;
  o[1] = lo.y;
  o[2] = hi.x;
  o[3] = hi.y;
}

// ---------------- degree (XCD-group-filtered: localizes atomics) ----------------
__global__ void k_deg(const int* __restrict__ row, int* __restrict__ deg) {
  int g = blockIdx.x & 7;
  int rlo = g * ROWS_PER_GROUP, rhi = min(N_NODES, rlo + ROWS_PER_GROUP);
  int bg = blockIdx.x >> 3, nbg = gridDim.x >> 3;
  for (int i = bg * 256 + threadIdx.x; i < N_EDGES; i += nbg * 256) {
    int r = row[i];
    if (r >= rlo && r < rhi) atomicAdd(&deg[r], 1);
  }
}

__global__ void k_disqrt(const int* __restrict__ deg, float* __restrict__ dis) {
  int i = blockIdx.x * blockDim.x + threadIdx.x;
  if (i < N_NODES) dis[i] = rsqrtf((float)(deg[i] + 1));
}

// ---------------- CSR build: 3-phase scan + XCD-localized scatter ----------------
__global__ void k_scan_part(const int* __restrict__ deg, int* __restrict__ bsum) {
  __shared__ int s[256];
  int t = threadIdx.x, i = blockIdx.x * 256 + t;
  s[t] = (i < N_NODES) ? deg[i] : 0;
  __syncthreads();
  for (int off = 128; off > 0; off >>= 1) {
    if (t < off) s[t] += s[t + off];
    __syncthreads();
  }
  if (t == 0) bsum[blockIdx.x] = s[0];
}

__global__ void k_scan_top(const int* __restrict__ bsum, int* __restrict__ boff, int nb) {
  __shared__ int s[256];
  int t = threadIdx.x;
  int v = (t < nb) ? bsum[t] : 0;
  s[t] = v;
  __syncthreads();
  for (int off = 1; off < 256; off <<= 1) {
    int x = (t >= off) ? s[t - off] : 0;
    __syncthreads();
    s[t] += x;
    __syncthreads();
  }
  if (t < nb) boff[t] = s[t] - v;  // exclusive
}

__global__ void k_scan_final(const int* __restrict__ deg, const int* __restrict__ boff,
                             int* __restrict__ row_start) {
  __shared__ int s[256];
  int t = threadIdx.x, i = blockIdx.x * 256 + t;
  int v = (i < N_NODES) ? deg[i] : 0;
  s[t] = v;
  __syncthreads();
  for (int off = 1; off < 256; off <<= 1) {
    int x = (t >= off) ? s[t - off] : 0;
    __syncthreads();
    s[t] += x;
    __syncthreads();
  }
  if (i < N_NODES) row_start[i] = boff[blockIdx.x] + s[t] - v;
  if (i == 0) row_start[N_NODES] = N_EDGES;
}

// group-filtered: each XCD-group handles 1/8 of the rows; writes+atomics localized.
__global__ void k_scatter(const int* __restrict__ row, const int* __restrict__ col,
                          const int* __restrict__ row_start, int* __restrict__ fill,
                          int* __restrict__ col_sorted) {
  int g = blockIdx.x & 7;
  int rlo = g * ROWS_PER_GROUP, rhi = min(N_NODES, rlo + ROWS_PER_GROUP);
  int bg = blockIdx.x >> 3, nbg = gridDim.x >> 3;
  for (int i = bg * 256 + threadIdx.x; i < N_EDGES; i += nbg * 256) {
    int r = row[i];
    if (r >= rlo && r < rhi) {
      int pos = row_start[r] + atomicAdd(&fill[r], 1);
      col_sorted[pos] = col[i];
    }
  }
}

// ---------------- W transpose to bf16: Wt[n][k] = bf16(W[k][n]) ----------------
__global__ void k_wt(const float* __restrict__ W, ushort* __restrict__ Wt, int K, int N) {
  int idx = blockIdx.x * 256 + threadIdx.x;
  if (idx >= K * N) return;
  int n = idx / K, k = idx % K;
  Wt[idx] = f2bf(W[(size_t)k * N + n]);
}

// ---------------- bf16 MFMA GEMM: hs = cvt( f(A) @ W * d_isqrt ) ----------------
template <int D, bool APPLY_BN, bool OUT_FP8>
__global__ __launch_bounds__(128 * (D / 64)) void k_gemm_bf16(const void* __restrict__ Av,
                                                              const ushort* __restrict__ Wt,
                                                              const float* __restrict__ ss,
                                                              const float* __restrict__ dis,
                                                              void* __restrict__ hsv) {
  constexpr int THREADS = 128 * (D / 64);  // 512 (D=256) / 256 (D=128)
  constexpr int BM = 128, BK = 32, K = 256;
  constexpr int WC = D / 64;
  constexpr int LDP = BK + 8;
  __shared__ ushort As[BM * LDP];
  __shared__ ushort Bs[D * LDP];
  const int tid = threadIdx.x;
  const int lane = tid & 63;
  const int wid = tid >> 6;
  const int wr = wid / WC, wc = wid % WC;
  const int rb = blockIdx.x * BM;

  f32x4 acc[4][4];
#pragma unroll
  for (int m = 0; m < 4; ++m)
#pragma unroll
    for (int n = 0; n < 4; ++n) acc[m][n] = (f32x4)(0.f);

  for (int kt = 0; kt < K; kt += BK) {
#pragma unroll
    for (int it = 0; it < 512 / THREADS; ++it) {
      int idx = tid + it * THREADS;
      int row = idx >> 2, kq = idx & 3;
      int gr = rb + row;
      if (gr >= N_NODES) gr = N_NODES - 1;
      float e[8];
      if constexpr (APPLY_BN) {
        const ushort* A = (const ushort*)Av;
        short8 v = *reinterpret_cast<const short8*>(&A[(size_t)gr * K + kt + kq * 8]);
#pragma unroll
        for (int q = 0; q < 8; ++q) {
          int k = kt + kq * 8 + q;
          e[q] = fmaxf(bf2f((ushort)v[q]) * ss[k] + ss[256 + k], 0.f);
        }
      } else {
        const float* A = (const float*)Av;
        const float4* src = reinterpret_cast<const float4*>(&A[(size_t)gr * K + kt + kq * 8]);
        float4 v0 = src[0], v1 = src[1];
        e[0] = v0.x; e[1] = v0.y; e[2] = v0.z; e[3] = v0.w;
        e[4] = v1.x; e[5] = v1.y; e[6] = v1.z; e[7] = v1.w;
      }
      short8 pk;
#pragma unroll
      for (int q = 0; q < 8; ++q) pk[q] = (short)f2bf(e[q]);
      *reinterpret_cast<short8*>(&As[row * LDP + kq * 8]) = pk;
    }
#pragma unroll
    for (int it = 0; it < D * 4 / THREADS; ++it) {
      int idx = tid + it * THREADS;
      int n = idx >> 2, kq = idx & 3;
      short8 v = *reinterpret_cast<const short8*>(&Wt[(size_t)n * K + kt + kq * 8]);
      *reinterpret_cast<short8*>(&Bs[n * LDP + kq * 8]) = v;
    }
    __syncthreads();

    const int rl = lane & 15;
    const int kb = (lane >> 4) * 8;
    short8 af[4], bfr[4];
#pragma unroll
    for (int f = 0; f < 4; ++f) {
      af[f] = *reinterpret_cast<short8*>(&As[(wr * 64 + f * 16 + rl) * LDP + kb]);
      bfr[f] = *reinterpret_cast<short8*>(&Bs[(wc * 64 + f * 16 + rl) * LDP + kb]);
    }
#pragma unroll
    for (int m = 0; m < 4; ++m)
#pragma unroll
      for (int n = 0; n < 4; ++n)
        acc[m][n] = __builtin_amdgcn_mfma_f32_16x16x32_bf16(af[m], bfr[n], acc[m][n], 0, 0, 0);
    __syncthreads();
  }

  const int cl = lane & 15;
  const int rq = lane >> 4;
#pragma unroll
  for (int m = 0; m < 4; ++m) {
    int rbase = rb + wr * 64 + m * 16 + rq * 4;
#pragma unroll
    for (int j = 0; j < 4; ++j) {
      int row = rbase + j;
      if (row >= N_NODES) continue;
      float di = dis[row];
#pragma unroll
      for (int n = 0; n < 4; ++n) {
        int col = wc * 64 + n * 16 + cl;
        if constexpr (OUT_FP8) {
          ((uchar*)hsv)[(size_t)row * D + col] = f2fp8(acc[m][n][j] * di);
        } else {
          ((ushort*)hsv)[(size_t)row * D + col] = f2bf(acc[m][n][j] * di);
        }
      }
    }
  }
}

// ---------------- fp8 aggregation: pre = bf16(dis*(self+sum_nbr)+b) ----------------
__global__ __launch_bounds__(256) void k_agg_fp8(const uchar* __restrict__ hs8,
                                                 const int* __restrict__ cs,
                                                 const int* __restrict__ rs,
                                                 const float* __restrict__ dis,
                                                 const float* __restrict__ bias,
                                                 ushort* __restrict__ pre) {
  int gw = (blockIdx.x * 256 + threadIdx.x) >> 6;
  if (gw >= N_NODES) return;
  const int lane = threadIdx.x & 63;
  const int quad = lane >> 4;
  const int c16 = lane & 15;
  const size_t coff = (size_t)c16 * 16;

  float a[16];
  {
    uint4 sv = *reinterpret_cast<const uint4*>(&hs8[(size_t)gw * 256 + coff]);
    float tmp[16];
    dec4(sv.x, tmp);
    dec4(sv.y, tmp + 4);
    dec4(sv.z, tmp + 8);
    dec4(sv.w, tmp + 12);
#pragma unroll
    for (int q = 0; q < 16; ++q) a[q] = quad ? 0.f : tmp[q];
  }

  int s = rs[gw], e = rs[gw + 1];
  for (int base = s; base < e; base += 64) {
    int nav = min(64, e - base);
    int idx = (base + lane < e) ? cs[base + lane] : 0;
    int j = 0;
    for (; j + 16 <= nav; j += 16) {  // 16 edges: 4 loads in flight
      uint4 v[4];
#pragma unroll
      for (int u = 0; u < 4; ++u) {
        int c = __shfl(idx, j + 4 * u + quad);
        v[u] = *reinterpret_cast<const uint4*>(&hs8[(size_t)((uint)c) * 256 + coff]);
      }
#pragma unroll
      for (int u = 0; u < 4; ++u) {
        float tmp[16];
        dec4(v[u].x, tmp);
        dec4(v[u].y, tmp + 4);
        dec4(v[u].z, tmp + 8);
        dec4(v[u].w, tmp + 12);
#pragma unroll
        for (int q = 0; q < 16; ++q) a[q] += tmp[q];
      }
    }
    for (; j < nav; j += 4) {  // tail: weight-folded quad-load
      int je = j + quad;
      int c = __shfl(idx, je & 63);
      float w = (je < nav) ? 1.f : 0.f;
      uint4 v = *reinterpret_cast<const uint4*>(&hs8[(size_t)((uint)c) * 256 + coff]);
      float tmp[16];
      dec4(v.x, tmp);
      dec4(v.y, tmp + 4);
      dec4(v.z, tmp + 8);
      dec4(v.w, tmp + 12);
#pragma unroll
      for (int q = 0; q < 16; ++q) a[q] = fmaf(w, tmp[q], a[q]);
    }
  }
#pragma unroll
  for (int q = 0; q < 16; ++q) {
    a[q] += __shfl_xor(a[q], 16);
    a[q] += __shfl_xor(a[q], 32);
  }

  if (quad == 0) {
    float di = dis[gw];
    float bb[16];
#pragma unroll
    for (int p = 0; p < 4; ++p) {
      float4 b = *reinterpret_cast<const float4*>(&bias[coff + p * 4]);
      bb[p * 4] = b.x;
      bb[p * 4 + 1] = b.y;
      bb[p * 4 + 2] = b.z;
      bb[p * 4 + 3] = b.w;
    }
    short8 o0, o1;
#pragma unroll
    for (int q = 0; q < 8; ++q) {
      o0[q] = (short)f2bf(a[q] * di + bb[q]);
      o1[q] = (short)f2bf(a[8 + q] * di + bb[8 + q]);
    }
    *reinterpret_cast<short8*>(&pre[(size_t)gw * 256 + coff]) = o0;
    *reinterpret_cast<short8*>(&pre[(size_t)gw * 256 + coff + 8]) = o1;
  }
}

// layer-3 agg + log_softmax: D=128 bf16 row = 256B = 16 lanes x short8; 4 edges/instr.
__global__ __launch_bounds__(256) void k_agg_lsm_bf16(const ushort* __restrict__ hs,
                                                      const int* __restrict__ cs,
                                                      const int* __restrict__ rs,
                                                      const float* __restrict__ dis,
                                                      const float* __restrict__ bias,
                                                      float* __restrict__ out) {
  int gw = (blockIdx.x * 256 + threadIdx.x) >> 6;
  if (gw >= N_NODES) return;
  const int lane = threadIdx.x & 63;
  const int quad = lane >> 4;
  const int c8 = lane & 15;
  const size_t coff = (size_t)c8 * 8;

  float a[8];
  short8 sv = *reinterpret_cast<const short8*>(&hs[(size_t)gw * 128 + coff]);
#pragma unroll
  for (int q = 0; q < 8; ++q) a[q] = quad ? 0.f : bf2f((ushort)sv[q]);

  int s = rs[gw], e = rs[gw + 1];
  for (int base = s; base < e; base += 64) {
    int nav = min(64, e - base);
    int idx = (base + lane < e) ? cs[base + lane] : 0;
    int j = 0;
    for (; j + 16 <= nav; j += 16) {
      short8 v[4];
#pragma unroll
      for (int u = 0; u < 4; ++u) {
        int c = __shfl(idx, j + 4 * u + quad);
        v[u] = *reinterpret_cast<const short8*>(&hs[(size_t)((uint)c) * 128 + coff]);
      }
#pragma unroll
      for (int u = 0; u < 4; ++u)
#pragma unroll
        for (int q = 0; q < 8; ++q) a[q] += bf2f((ushort)v[u][q]);
    }
    for (; j < nav; j += 4) {
      int je = j + quad;
      int c = __shfl(idx, je & 63);
      float w = (je < nav) ? 1.f : 0.f;
      short8 v = *reinterpret_cast<const short8*>(&hs[(size_t)((uint)c) * 128 + coff]);
#pragma unroll
      for (int q = 0; q < 8; ++q) a[q] = fmaf(w, bf2f((ushort)v[q]), a[q]);
    }
  }
#pragma unroll
  for (int q = 0; q < 8; ++q) {
    a[q] += __shfl_xor(a[q], 16);
    a[q] += __shfl_xor(a[q], 32);
  }

  float di = dis[gw];
  float4 b0 = *reinterpret_cast<const float4*>(&bias[c8 * 8]);
  float4 b1 = *reinterpret_cast<const float4*>(&bias[c8 * 8 + 4]);
  float bb[8] = {b0.x, b0.y, b0.z, b0.w, b1.x, b1.y, b1.z, b1.w};
  float vv[8];
  float m = -1e30f;
#pragma unroll
  for (int q = 0; q < 8; ++q) {
    vv[q] = a[q] * di + bb[q];
    m = fmaxf(m, vv[q]);
  }
#pragma unroll
  for (int o = 1; o < 16; o <<= 1) m = fmaxf(m, __shfl_xor(m, o));
  float sum = 0.f;
#pragma unroll
  for (int q = 0; q < 8; ++q) sum += __expf(vv[q] - m);
#pragma unroll
  for (int o = 1; o < 16; o <<= 1) sum += __shfl_xor(sum, o);
  float ls = m + logf(sum);
  if (quad == 0) {
    float4 o0 = {vv[0] - ls, vv[1] - ls, vv[2] - ls, vv[3] - ls};
    float4 o1 = {vv[4] - ls, vv[5] - ls, vv[6] - ls, vv[7] - ls};
    *reinterpret_cast<float4*>(&out[(size_t)gw * 128 + coff]) = o0;
    *reinterpret_cast<float4*>(&out[(size_t)gw * 128 + coff + 4]) = o1;
  }
}

// ---------------- batchnorm stats: three-phase, atomic-free ----------------
__global__ __launch_bounds__(256) void k_bnstatsA(const ushort* __restrict__ pre,
                                                  float* __restrict__ partial) {
  int t = threadIdx.x;
  int rsub = t >> 7;
  int cp = (t & 127) * 2;
  float s0 = 0.f, s1 = 0.f, q0 = 0.f, q1 = 0.f;
  for (int r = blockIdx.x * 2 + rsub; r < N_NODES; r += BNA_BLOCKS * 2) {
    ushort2 v = *reinterpret_cast<const ushort2*>(&pre[(size_t)r * 256 + cp]);
    float f0 = bf2f(v.x), f1 = bf2f(v.y);
    s0 += f0;
    q0 += f0 * f0;
    s1 += f1;
    q1 += f1 * f1;
  }
  __shared__ float lsum[256], lsq[256];
  if (rsub) {
    lsum[cp] = s0;
    lsum[cp + 1] = s1;
    lsq[cp] = q0;
    lsq[cp + 1] = q1;
  }
  __syncthreads();
  if (!rsub) {
    float* p = &partial[(size_t)blockIdx.x * 512];
    p[cp] = s0 + lsum[cp];
    p[cp + 1] = s1 + lsum[cp + 1];
    p[256 + cp] = q0 + lsq[cp];
    p[256 + cp + 1] = q1 + lsq[cp + 1];
  }
}

__global__ __launch_bounds__(512) void k_bnstatsB(const float* __restrict__ partial,
                                                  float* __restrict__ p2) {
  int t = threadIdx.x, b = blockIdx.x;
  float a = 0.f;
#pragma unroll 8
  for (int r = 0; r < BNA_BLOCKS / 8; ++r)
    a += partial[(size_t)(b * (BNA_BLOCKS / 8) + r) * 512 + t];
  p2[(size_t)b * 512 + t] = a;
}

__global__ void k_bnfinal(const float* __restrict__ p2, const float* __restrict__ gamma,
                          const float* __restrict__ beta, float* __restrict__ ss) {
  int t = threadIdx.x;
  float sum = 0.f, sq = 0.f;
#pragma unroll
  for (int b = 0; b < 8; ++b) {
    sum += p2[(size_t)b * 512 + t];
    sq += p2[(size_t)b * 512 + 256 + t];
  }
  float mu = sum * (1.f / N_NODES);
  float var = sq * (1.f / N_NODES) - mu * mu;
  float sc = gamma[t] * rsqrtf(var + BN_EPS);
  ss[t] = sc;
  ss[256 + t] = beta[t] - mu * sc;
}

// ---------------- launcher ----------------
extern "C" void kernel_launch(void* const* d_in, const int* in_sizes, int n_in,
                              void* d_out, int out_size, void* d_ws, size_t ws_size,
                              hipStream_t stream) {
  const float* x = (const float*)d_in[0];
  const int* erow = (const int*)d_in[1];
  const int* ecol = erow + N_EDGES;
  const float* W0 = (const float*)d_in[2];
  const float* b0 = (const float*)d_in[3];
  const float* W1 = (const float*)d_in[4];
  const float* b1 = (const float*)d_in[5];
  const float* W2 = (const float*)d_in[6];
  const float* b2 = (const float*)d_in[7];
  const float* g0 = (const float*)d_in[8];
  const float* be0 = (const float*)d_in[9];
  const float* g1 = (const float*)d_in[10];
  const float* be1 = (const float*)d_in[11];
  float* out = (float*)d_out;

  char* ws = (char*)d_ws;
  size_t off = 0;
  auto take = [&](size_t bytes) {
    char* p = ws + off;
    off = (off + bytes + 255) & ~(size_t)255;
    return p;
  };
  int* deg = (int*)take(N_NODES * 4);
  int* fill = (int*)take(N_NODES * 4);
  size_t zero_bytes = off;  // deg+fill must start at 0 each call
  float* bnpart = (float*)take((size_t)BNA_BLOCKS * 512 * 4);
  float* bnpart2 = (float*)take(8 * 512 * 4);
  float* dis = (float*)take(N_NODES * 4);
  int* row_start = (int*)take((N_NODES + 1) * 4);
  int* bsum = (int*)take(256 * 4);
  int* boff = (int*)take(256 * 4);
  float* ss0 = (float*)take(512 * 4);
  float* ss1 = (float*)take(512 * 4);
  ushort* Wt0 = (ushort*)take(256 * 256 * 2);
  ushort* Wt1 = (ushort*)take(256 * 256 * 2);
  ushort* Wt2 = (ushort*)take(256 * 128 * 2);
  int* col_sorted = (int*)take((size_t)N_EDGES * 4);
  uchar* hs8 = (uchar*)take((size_t)N_NODES * 256);        // fp8 gather operand (L0/L1)
  ushort* hs = (ushort*)take((size_t)N_NODES * 128 * 2);   // bf16 (L2)
  ushort* pre = (ushort*)take((size_t)N_NODES * 256 * 2);  // bf16
  if (off > ws_size) return;

  hipMemsetAsync(d_ws, 0, zero_bytes, stream);

  k_deg<<<2048, 256, 0, stream>>>(erow, deg);
  k_disqrt<<<(N_NODES + 255) / 256, 256, 0, stream>>>(deg, dis);
  int nb = (N_NODES + 255) / 256;  // 196
  k_scan_part<<<nb, 256, 0, stream>>>(deg, bsum);
  k_scan_top<<<1, 256, 0, stream>>>(bsum, boff, nb);
  k_scan_final<<<nb, 256, 0, stream>>>(deg, boff, row_start);
  k_scatter<<<2048, 256, 0, stream>>>(erow, ecol, row_start, fill, col_sorted);

  k_wt<<<(256 * 256 + 255) / 256, 256, 0, stream>>>(W0, Wt0, 256, 256);
  k_wt<<<(256 * 256 + 255) / 256, 256, 0, stream>>>(W1, Wt1, 256, 256);
  k_wt<<<(256 * 128 + 255) / 256, 256, 0, stream>>>(W2, Wt2, 256, 128);

  int mblocks = (N_NODES + 127) / 128;        // 391
  int agg_grid = (N_NODES * 64 + 255) / 256;  // 12500
  // layer 0 (hs fp8)
  k_gemm_bf16<256, false, true><<<mblocks, 512, 0, stream>>>(x, Wt0, nullptr, dis, hs8);
  k_agg_fp8<<<agg_grid, 256, 0, stream>>>(hs8, col_sorted, row_start, dis, b0, pre);
  k_bnstatsA<<<BNA_BLOCKS, 256, 0, stream>>>(pre, bnpart);
  k_bnstatsB<<<8, 512, 0, stream>>>(bnpart, bnpart2);
  k_bnfinal<<<1, 256, 0, stream>>>(bnpart2, g0, be0, ss0);
  // layer 1 (hs fp8)
  k_gemm_bf16<256, true, true><<<mblocks, 512, 0, stream>>>(pre, Wt1, ss0, dis, hs8);
  k_agg_fp8<<<agg_grid, 256, 0, stream>>>(hs8, col_sorted, row_start, dis, b1, pre);
  k_bnstatsA<<<BNA_BLOCKS, 256, 0, stream>>>(pre, bnpart);
  k_bnstatsB<<<8, 512, 0, stream>>>(bnpart, bnpart2);
  k_bnfinal<<<1, 256, 0, stream>>>(bnpart2, g1, be1, ss1);
  // layer 2 (bf16) + fused log_softmax
  k_gemm_bf16<128, true, false><<<mblocks, 256, 0, stream>>>(pre, Wt2, ss1, dis, hs);
  k_agg_lsm_bf16<<<agg_grid, 256, 0, stream>>>(hs, col_sorted, row_start, dis, b2, out);
}

// Round 16
// 262.618 us; speedup vs baseline: 1.8248x; 1.2069x over previous
//
#include <hip/hip_runtime.h>

constexpr int N_NODES = 50000;
constexpr int N_EDGES = 800000;
constexpr float BN_EPS = 1e-5f;
constexpr int BNA_BLOCKS = 256;
constexpr int EBLK = 256;            // edge blocks for radix pass 1
constexpr int EPB = N_EDGES / EBLK;  // 3125 (exact)
constexpr int NBUCK = (N_NODES + 255) / 256;  // 196 row-buckets

typedef __attribute__((ext_vector_type(8))) short short8;
typedef __attribute__((ext_vector_type(4))) float f32x4;
typedef __attribute__((ext_vector_type(2))) float f32x2;

__device__ __forceinline__ float bf2f(ushort u) {
  union { uint i; float f; } v;
  v.i = ((uint)u) << 16;
  return v.f;
}
__device__ __forceinline__ ushort f2bf(float f) {
  union { float f; uint i; } v;
  v.f = f;
  uint r = v.i + 0x7fff + ((v.i >> 16) & 1);  // RNE
  return (ushort)(r >> 16);
}
__device__ __forceinline__ uchar f2fp8(float v) {
  int r = __builtin_amdgcn_cvt_pk_fp8_f32(v, 0.f, 0, false);
  return (uchar)(r & 0xff);
}
__device__ __forceinline__ void dec4(uint w, float* o) {
  f32x2 lo = __builtin_amdgcn_cvt_pk_f32_fp8(w, false);
  f32x2 hi = __builtin_amdgcn_cvt_pk_f32_fp8(w, true);
  o[0] = lo.x;
  o[1] = lo.y;
  o[2] = hi.x;
  o[3] = hi.y;
}

// ================= CSR build: atomic-free 2-pass radix sort by row =================
// pass 1a: per-edge-block histogram of row>>8 (196 buckets used of 256)
__global__ __launch_bounds__(256) void k_ehist(const int* __restrict__ erow,
                                               int* __restrict__ bh) {
  __shared__ int h[256];
  int t = threadIdx.x;
  h[t] = 0;
  __syncthreads();
  int base = blockIdx.x * EPB;
  for (int i = t; i < EPB; i += 256) atomicAdd(&h[erow[base + i] >> 8], 1);
  __syncthreads();
  bh[blockIdx.x * 256 + t] = h[t];
}

// pass 1b: per-bucket prefix over edge-blocks (256 blocks = one bucket each)
__global__ void k_binscanA(const int* __restrict__ bh, int* __restrict__ bhoff,
                           int* __restrict__ btot, int nb) {
  __shared__ int s[256];
  int b = blockIdx.x;   // bucket
  int t = threadIdx.x;  // edge-block index
  int v = (t < nb) ? bh[t * 256 + b] : 0;
  s[t] = v;
  __syncthreads();
  for (int off = 1; off < 256; off <<= 1) {
    int x = (t >= off) ? s[t - off] : 0;
    __syncthreads();
    s[t] += x;
    __syncthreads();
  }
  if (t < nb) bhoff[t * 256 + b] = s[t] - v;
  if (t == 255) btot[b] = s[255];
}

// pass 1c: global bucket prefix; also seals row_start[N] = E
__global__ void k_binscanB(const int* __restrict__ btot, int* __restrict__ bucketStart,
                           int* __restrict__ row_start) {
  __shared__ int s[256];
  int t = threadIdx.x;
  int v = btot[t];
  s[t] = v;
  __syncthreads();
  for (int off = 1; off < 256; off <<= 1) {
    int x = (t >= off) ? s[t - off] : 0;
    __syncthreads();
    s[t] += x;
    __syncthreads();
  }
  bucketStart[t] = s[t] - v;  // exclusive
  if (t == 0) row_start[N_NODES] = N_EDGES;
}

// pass 2: scatter edges into buckets, packed (row&255)<<16 | col  (col < 65536)
__global__ __launch_bounds__(256) void k_escatter(const int* __restrict__ erow,
                                                  const int* __restrict__ ecol,
                                                  const int* __restrict__ bucketStart,
                                                  const int* __restrict__ bhoff,
                                                  int* __restrict__ ebuf) {
  __shared__ int fl[256];
  int t = threadIdx.x;
  fl[t] = 0;
  __syncthreads();
  int b = blockIdx.x, base = b * EPB;
  for (int i = t; i < EPB; i += 256) {
    int r = erow[base + i], c = ecol[base + i];
    int bin = r >> 8;
    int rk = atomicAdd(&fl[bin], 1);
    int pos = bucketStart[bin] + bhoff[b * 256 + bin] + rk;
    ebuf[pos] = ((r & 255) << 16) | c;
  }
}

// pass 3: sort within bucket by row&255 (LDS hist+scan), emit row_start/deg/col_sorted
__global__ __launch_bounds__(256) void k_esort(const int* __restrict__ ebuf,
                                               const int* __restrict__ bucketStart,
                                               const int* __restrict__ btot,
                                               int* __restrict__ col_sorted,
                                               int* __restrict__ row_start,
                                               int* __restrict__ deg) {
  __shared__ int h[256], pex[256], fl[256], sc[256];
  int bin = blockIdx.x, t = threadIdx.x;
  int base = bucketStart[bin], n = btot[bin];
  h[t] = 0;
  fl[t] = 0;
  __syncthreads();
  for (int i = t; i < n; i += 256) atomicAdd(&h[ebuf[base + i] >> 16], 1);
  __syncthreads();
  int v = h[t];
  sc[t] = v;
  __syncthreads();
  for (int off = 1; off < 256; off <<= 1) {
    int x = (t >= off) ? sc[t - off] : 0;
    __syncthreads();
    sc[t] += x;
    __syncthreads();
  }
  pex[t] = sc[t] - v;  // exclusive prefix within bucket
  int row = bin * 256 + t;
  if (row < N_NODES) {
    row_start[row] = base + pex[t];
    deg[row] = v;
  }
  __syncthreads();
  for (int i = t; i < n; i += 256) {
    int e = ebuf[base + i];
    int rl = e >> 16;
    int rk = atomicAdd(&fl[rl], 1);
    col_sorted[base + pex[rl] + rk] = e & 0xFFFF;
  }
}

__global__ void k_disqrt(const int* __restrict__ deg, float* __restrict__ dis) {
  int i = blockIdx.x * blockDim.x + threadIdx.x;
  if (i < N_NODES) dis[i] = rsqrtf((float)(deg[i] + 1));
}

// ---------------- W transpose to bf16: Wt[n][k] = bf16(W[k][n]) ----------------
__global__ void k_wt(const float* __restrict__ W, ushort* __restrict__ Wt, int K, int N) {
  int idx = blockIdx.x * 256 + threadIdx.x;
  if (idx >= K * N) return;
  int n = idx / K, k = idx % K;
  Wt[idx] = f2bf(W[(size_t)k * N + n]);
}

// ---------------- bf16 MFMA GEMM: hs = cvt( f(A) @ W * d_isqrt ) ----------------
template <int D, bool APPLY_BN, bool OUT_FP8>
__global__ __launch_bounds__(128 * (D / 64)) void k_gemm_bf16(const void* __restrict__ Av,
                                                              const ushort* __restrict__ Wt,
                                                              const float* __restrict__ ss,
                                                              const float* __restrict__ dis,
                                                              void* __restrict__ hsv) {
  constexpr int THREADS = 128 * (D / 64);  // 512 (D=256) / 256 (D=128)
  constexpr int BM = 128, BK = 32, K = 256;
  constexpr int WC = D / 64;
  constexpr int LDP = BK + 8;
  __shared__ ushort As[BM * LDP];
  __shared__ ushort Bs[D * LDP];
  const int tid = threadIdx.x;
  const int lane = tid & 63;
  const int wid = tid >> 6;
  const int wr = wid / WC, wc = wid % WC;
  const int rb = blockIdx.x * BM;

  f32x4 acc[4][4];
#pragma unroll
  for (int m = 0; m < 4; ++m)
#pragma unroll
    for (int n = 0; n < 4; ++n) acc[m][n] = (f32x4)(0.f);

  for (int kt = 0; kt < K; kt += BK) {
#pragma unroll
    for (int it = 0; it < 512 / THREADS; ++it) {
      int idx = tid + it * THREADS;
      int row = idx >> 2, kq = idx & 3;
      int gr = rb + row;
      if (gr >= N_NODES) gr = N_NODES - 1;
      float e[8];
      if constexpr (APPLY_BN) {
        const ushort* A = (const ushort*)Av;
        short8 v = *reinterpret_cast<const short8*>(&A[(size_t)gr * K + kt + kq * 8]);
#pragma unroll
        for (int q = 0; q < 8; ++q) {
          int k = kt + kq * 8 + q;
          e[q] = fmaxf(bf2f((ushort)v[q]) * ss[k] + ss[256 + k], 0.f);
        }
      } else {
        const float* A = (const float*)Av;
        const float4* src = reinterpret_cast<const float4*>(&A[(size_t)gr * K + kt + kq * 8]);
        float4 v0 = src[0], v1 = src[1];
        e[0] = v0.x; e[1] = v0.y; e[2] = v0.z; e[3] = v0.w;
        e[4] = v1.x; e[5] = v1.y; e[6] = v1.z; e[7] = v1.w;
      }
      short8 pk;
#pragma unroll
      for (int q = 0; q < 8; ++q) pk[q] = (short)f2bf(e[q]);
      *reinterpret_cast<short8*>(&As[row * LDP + kq * 8]) = pk;
    }
#pragma unroll
    for (int it = 0; it < D * 4 / THREADS; ++it) {
      int idx = tid + it * THREADS;
      int n = idx >> 2, kq = idx & 3;
      short8 v = *reinterpret_cast<const short8*>(&Wt[(size_t)n * K + kt + kq * 8]);
      *reinterpret_cast<short8*>(&Bs[n * LDP + kq * 8]) = v;
    }
    __syncthreads();

    const int rl = lane & 15;
    const int kb = (lane >> 4) * 8;
    short8 af[4], bfr[4];
#pragma unroll
    for (int f = 0; f < 4; ++f) {
      af[f] = *reinterpret_cast<short8*>(&As[(wr * 64 + f * 16 + rl) * LDP + kb]);
      bfr[f] = *reinterpret_cast<short8*>(&Bs[(wc * 64 + f * 16 + rl) * LDP + kb]);
    }
#pragma unroll
    for (int m = 0; m < 4; ++m)
#pragma unroll
      for (int n = 0; n < 4; ++n)
        acc[m][n] = __builtin_amdgcn_mfma_f32_16x16x32_bf16(af[m], bfr[n], acc[m][n], 0, 0, 0);
    __syncthreads();
  }

  const int cl = lane & 15;
  const int rq = lane >> 4;
#pragma unroll
  for (int m = 0; m < 4; ++m) {
    int rbase = rb + wr * 64 + m * 16 + rq * 4;
#pragma unroll
    for (int j = 0; j < 4; ++j) {
      int row = rbase + j;
      if (row >= N_NODES) continue;
      float di = dis[row];
#pragma unroll
      for (int n = 0; n < 4; ++n) {
        int col = wc * 64 + n * 16 + cl;
        if constexpr (OUT_FP8) {
          ((uchar*)hsv)[(size_t)row * D + col] = f2fp8(acc[m][n][j] * di);
        } else {
          ((ushort*)hsv)[(size_t)row * D + col] = f2bf(acc[m][n][j] * di);
        }
      }
    }
  }
}

// ---------------- fp8 aggregation: pre = bf16(dis*(self+sum_nbr)+b) ----------------
__global__ __launch_bounds__(256) void k_agg_fp8(const uchar* __restrict__ hs8,
                                                 const int* __restrict__ cs,
                                                 const int* __restrict__ rs,
                                                 const float* __restrict__ dis,
                                                 const float* __restrict__ bias,
                                                 ushort* __restrict__ pre) {
  int gw = (blockIdx.x * 256 + threadIdx.x) >> 6;
  if (gw >= N_NODES) return;
  const int lane = threadIdx.x & 63;
  const int quad = lane >> 4;
  const int c16 = lane & 15;
  const size_t coff = (size_t)c16 * 16;

  float a[16];
  {
    uint4 sv = *reinterpret_cast<const uint4*>(&hs8[(size_t)gw * 256 + coff]);
    float tmp[16];
    dec4(sv.x, tmp);
    dec4(sv.y, tmp + 4);
    dec4(sv.z, tmp + 8);
    dec4(sv.w, tmp + 12);
#pragma unroll
    for (int q = 0; q < 16; ++q) a[q] = quad ? 0.f : tmp[q];
  }

  int s = rs[gw], e = rs[gw + 1];
  for (int base = s; base < e; base += 64) {
    int nav = min(64, e - base);
    int idx = (base + lane < e) ? cs[base + lane] : 0;
    int j = 0;
    for (; j + 16 <= nav; j += 16) {  // 16 edges: 4 loads in flight
      uint4 v[4];
#pragma unroll
      for (int u = 0; u < 4; ++u) {
        int c = __shfl(idx, j + 4 * u + quad);
        v[u] = *reinterpret_cast<const uint4*>(&hs8[(size_t)((uint)c) * 256 + coff]);
      }
#pragma unroll
      for (int u = 0; u < 4; ++u) {
        float tmp[16];
        dec4(v[u].x, tmp);
        dec4(v[u].y, tmp + 4);
        dec4(v[u].z, tmp + 8);
        dec4(v[u].w, tmp + 12);
#pragma unroll
        for (int q = 0; q < 16; ++q) a[q] += tmp[q];
      }
    }
    for (; j < nav; j += 4) {  // tail: weight-folded quad-load
      int je = j + quad;
      int c = __shfl(idx, je & 63);
      float w = (je < nav) ? 1.f : 0.f;
      uint4 v = *reinterpret_cast<const uint4*>(&hs8[(size_t)((uint)c) * 256 + coff]);
      float tmp[16];
      dec4(v.x, tmp);
      dec4(v.y, tmp + 4);
      dec4(v.z, tmp + 8);
      dec4(v.w, tmp + 12);
#pragma unroll
      for (int q = 0; q < 16; ++q) a[q] = fmaf(w, tmp[q], a[q]);
    }
  }
#pragma unroll
  for (int q = 0; q < 16; ++q) {
    a[q] += __shfl_xor(a[q], 16);
    a[q] += __shfl_xor(a[q], 32);
  }

  if (quad == 0) {
    float di = dis[gw];
    float bb[16];
#pragma unroll
    for (int p = 0; p < 4; ++p) {
      float4 b = *reinterpret_cast<const float4*>(&bias[coff + p * 4]);
      bb[p * 4] = b.x;
      bb[p * 4 + 1] = b.y;
      bb[p * 4 + 2] = b.z;
      bb[p * 4 + 3] = b.w;
    }
    short8 o0, o1;
#pragma unroll
    for (int q = 0; q < 8; ++q) {
      o0[q] = (short)f2bf(a[q] * di + bb[q]);
      o1[q] = (short)f2bf(a[8 + q] * di + bb[8 + q]);
    }
    *reinterpret_cast<short8*>(&pre[(size_t)gw * 256 + coff]) = o0;
    *reinterpret_cast<short8*>(&pre[(size_t)gw * 256 + coff + 8]) = o1;
  }
}

// layer-3 agg + log_softmax: D=128 bf16 row = 256B = 16 lanes x short8; 4 edges/instr.
__global__ __launch_bounds__(256) void k_agg_lsm_bf16(const ushort* __restrict__ hs,
                                                      const int* __restrict__ cs,
                                                      const int* __restrict__ rs,
                                                      const float* __restrict__ dis,
                                                      const float* __restrict__ bias,
                                                      float* __restrict__ out) {
  int gw = (blockIdx.x * 256 + threadIdx.x) >> 6;
  if (gw >= N_NODES) return;
  const int lane = threadIdx.x & 63;
  const int quad = lane >> 4;
  const int c8 = lane & 15;
  const size_t coff = (size_t)c8 * 8;

  float a[8];
  short8 sv = *reinterpret_cast<const short8*>(&hs[(size_t)gw * 128 + coff]);
#pragma unroll
  for (int q = 0; q < 8; ++q) a[q] = quad ? 0.f : bf2f((ushort)sv[q]);

  int s = rs[gw], e = rs[gw + 1];
  for (int base = s; base < e; base += 64) {
    int nav = min(64, e - base);
    int idx = (base + lane < e) ? cs[base + lane] : 0;
    int j = 0;
    for (; j + 16 <= nav; j += 16) {
      short8 v[4];
#pragma unroll
      for (int u = 0; u < 4; ++u) {
        int c = __shfl(idx, j + 4 * u + quad);
        v[u] = *reinterpret_cast<const short8*>(&hs[(size_t)((uint)c) * 128 + coff]);
      }
#pragma unroll
      for (int u = 0; u < 4; ++u)
#pragma unroll
        for (int q = 0; q < 8; ++q) a[q] += bf2f((ushort)v[u][q]);
    }
    for (; j < nav; j += 4) {
      int je = j + quad;
      int c = __shfl(idx, je & 63);
      float w = (je < nav) ? 1.f : 0.f;
      short8 v = *reinterpret_cast<const short8*>(&hs[(size_t)((uint)c) * 128 + coff]);
#pragma unroll
      for (int q = 0; q < 8; ++q) a[q] = fmaf(w, bf2f((ushort)v[q]), a[q]);
    }
  }
#pragma unroll
  for (int q = 0; q < 8; ++q) {
    a[q] += __shfl_xor(a[q], 16);
    a[q] += __shfl_xor(a[q], 32);
  }

  float di = dis[gw];
  float4 b0 = *reinterpret_cast<const float4*>(&bias[c8 * 8]);
  float4 b1 = *reinterpret_cast<const float4*>(&bias[c8 * 8 + 4]);
  float bb[8] = {b0.x, b0.y, b0.z, b0.w, b1.x, b1.y, b1.z, b1.w};
  float vv[8];
  float m = -1e30f;
#pragma unroll
  for (int q = 0; q < 8; ++q) {
    vv[q] = a[q] * di + bb[q];
    m = fmaxf(m, vv[q]);
  }
#pragma unroll
  for (int o = 1; o < 16; o <<= 1) m = fmaxf(m, __shfl_xor(m, o));
  float sum = 0.f;
#pragma unroll
  for (int q = 0; q < 8; ++q) sum += __expf(vv[q] - m);
#pragma unroll
  for (int o = 1; o < 16; o <<= 1) sum += __shfl_xor(sum, o);
  float ls = m + logf(sum);
  if (quad == 0) {
    float4 o0 = {vv[0] - ls, vv[1] - ls, vv[2] - ls, vv[3] - ls};
    float4 o1 = {vv[4] - ls, vv[5] - ls, vv[6] - ls, vv[7] - ls};
    *reinterpret_cast<float4*>(&out[(size_t)gw * 128 + coff]) = o0;
    *reinterpret_cast<float4*>(&out[(size_t)gw * 128 + coff + 4]) = o1;
  }
}

// ---------------- batchnorm stats: three-phase, atomic-free ----------------
__global__ __launch_bounds__(256) void k_bnstatsA(const ushort* __restrict__ pre,
                                                  float* __restrict__ partial) {
  int t = threadIdx.x;
  int rsub = t >> 7;
  int cp = (t & 127) * 2;
  float s0 = 0.f, s1 = 0.f, q0 = 0.f, q1 = 0.f;
  for (int r = blockIdx.x * 2 + rsub; r < N_NODES; r += BNA_BLOCKS * 2) {
    ushort2 v = *reinterpret_cast<const ushort2*>(&pre[(size_t)r * 256 + cp]);
    float f0 = bf2f(v.x), f1 = bf2f(v.y);
    s0 += f0;
    q0 += f0 * f0;
    s1 += f1;
    q1 += f1 * f1;
  }
  __shared__ float lsum[256], lsq[256];
  if (rsub) {
    lsum[cp] = s0;
    lsum[cp + 1] = s1;
    lsq[cp] = q0;
    lsq[cp + 1] = q1;
  }
  __syncthreads();
  if (!rsub) {
    float* p = &partial[(size_t)blockIdx.x * 512];
    p[cp] = s0 + lsum[cp];
    p[cp + 1] = s1 + lsum[cp + 1];
    p[256 + cp] = q0 + lsq[cp];
    p[256 + cp + 1] = q1 + lsq[cp + 1];
  }
}

__global__ __launch_bounds__(512) void k_bnstatsB(const float* __restrict__ partial,
                                                  float* __restrict__ p2) {
  int t = threadIdx.x, b = blockIdx.x;
  float a = 0.f;
#pragma unroll 8
  for (int r = 0; r < BNA_BLOCKS / 8; ++r)
    a += partial[(size_t)(b * (BNA_BLOCKS / 8) + r) * 512 + t];
  p2[(size_t)b * 512 + t] = a;
}

__global__ void k_bnfinal(const float* __restrict__ p2, const float* __restrict__ gamma,
                          const float* __restrict__ beta, float* __restrict__ ss) {
  int t = threadIdx.x;
  float sum = 0.f, sq = 0.f;
#pragma unroll
  for (int b = 0; b < 8; ++b) {
    sum += p2[(size_t)b * 512 + t];
    sq += p2[(size_t)b * 512 + 256 + t];
  }
  float mu = sum * (1.f / N_NODES);
  float var = sq * (1.f / N_NODES) - mu * mu;
  float sc = gamma[t] * rsqrtf(var + BN_EPS);
  ss[t] = sc;
  ss[256 + t] = beta[t] - mu * sc;
}

// ---------------- launcher ----------------
extern "C" void kernel_launch(void* const* d_in, const int* in_sizes, int n_in,
                              void* d_out, int out_size, void* d_ws, size_t ws_size,
                              hipStream_t stream) {
  const float* x = (const float*)d_in[0];
  const int* erow = (const int*)d_in[1];
  const int* ecol = erow + N_EDGES;
  const float* W0 = (const float*)d_in[2];
  const float* b0 = (const float*)d_in[3];
  const float* W1 = (const float*)d_in[4];
  const float* b1 = (const float*)d_in[5];
  const float* W2 = (const float*)d_in[6];
  const float* b2 = (const float*)d_in[7];
  const float* g0 = (const float*)d_in[8];
  const float* be0 = (const float*)d_in[9];
  const float* g1 = (const float*)d_in[10];
  const float* be1 = (const float*)d_in[11];
  float* out = (float*)d_out;

  char* ws = (char*)d_ws;
  size_t off = 0;
  auto take = [&](size_t bytes) {
    char* p = ws + off;
    off = (off + bytes + 255) & ~(size_t)255;
    return p;
  };
  int* bh = (int*)take(256 * 256 * 4);
  int* bhoff = (int*)take(256 * 256 * 4);
  int* btot = (int*)take(256 * 4);
  int* bucketStart = (int*)take(256 * 4);
  int* ebuf = (int*)take((size_t)N_EDGES * 4);
  int* deg = (int*)take(N_NODES * 4);
  int* row_start = (int*)take((N_NODES + 1) * 4);
  float* bnpart = (float*)take((size_t)BNA_BLOCKS * 512 * 4);
  float* bnpart2 = (float*)take(8 * 512 * 4);
  float* dis = (float*)take(N_NODES * 4);
  float* ss0 = (float*)take(512 * 4);
  float* ss1 = (float*)take(512 * 4);
  ushort* Wt0 = (ushort*)take(256 * 256 * 2);
  ushort* Wt1 = (ushort*)take(256 * 256 * 2);
  ushort* Wt2 = (ushort*)take(256 * 128 * 2);
  int* col_sorted = (int*)take((size_t)N_EDGES * 4);
  uchar* hs8 = (uchar*)take((size_t)N_NODES * 256);        // fp8 gather operand (L0/L1)
  ushort* hs = (ushort*)take((size_t)N_NODES * 128 * 2);   // bf16 (L2)
  ushort* pre = (ushort*)take((size_t)N_NODES * 256 * 2);  // bf16
  if (off > ws_size) return;

  // CSR build: radix sort by row, no global atomics, no memset
  k_ehist<<<EBLK, 256, 0, stream>>>(erow, bh);
  k_binscanA<<<256, 256, 0, stream>>>(bh, bhoff, btot, EBLK);
  k_binscanB<<<1, 256, 0, stream>>>(btot, bucketStart, row_start);
  k_escatter<<<EBLK, 256, 0, stream>>>(erow, ecol, bucketStart, bhoff, ebuf);
  k_esort<<<NBUCK, 256, 0, stream>>>(ebuf, bucketStart, btot, col_sorted, row_start, deg);
  k_disqrt<<<(N_NODES + 255) / 256, 256, 0, stream>>>(deg, dis);

  k_wt<<<(256 * 256 + 255) / 256, 256, 0, stream>>>(W0, Wt0, 256, 256);
  k_wt<<<(256 * 256 + 255) / 256, 256, 0, stream>>>(W1, Wt1, 256, 256);
  k_wt<<<(256 * 128 + 255) / 256, 256, 0, stream>>>(W2, Wt2, 256, 128);

  int mblocks = (N_NODES + 127) / 128;        // 391
  int agg_grid = (N_NODES * 64 + 255) / 256;  // 12500
  // layer 0 (hs fp8)
  k_gemm_bf16<256, false, true><<<mblocks, 512, 0, stream>>>(x, Wt0, nullptr, dis, hs8);
  k_agg_fp8<<<agg_grid, 256, 0, stream>>>(hs8, col_sorted, row_start, dis, b0, pre);
  k_bnstatsA<<<BNA_BLOCKS, 256, 0, stream>>>(pre, bnpart);
  k_bnstatsB<<<8, 512, 0, stream>>>(bnpart, bnpart2);
  k_bnfinal<<<1, 256, 0, stream>>>(bnpart2, g0, be0, ss0);
  // layer 1 (hs fp8)
  k_gemm_bf16<256, true, true><<<mblocks, 512, 0, stream>>>(pre, Wt1, ss0, dis, hs8);
  k_agg_fp8<<<agg_grid, 256, 0, stream>>>(hs8, col_sorted, row_start, dis, b1, pre);
  k_bnstatsA<<<BNA_BLOCKS, 256, 0, stream>>>(pre, bnpart);
  k_bnstatsB<<<8, 512, 0, stream>>>(bnpart, bnpart2);
  k_bnfinal<<<1, 256, 0, stream>>>(bnpart2, g1, be1, ss1);
  // layer 2 (bf16) + fused log_softmax
  k_gemm_bf16<128, true, false><<<mblocks, 256, 0, stream>>>(pre, Wt2, ss1, dis, hs);
  k_agg_lsm_bf16<<<agg_grid, 256, 0, stream>>>(hs, col_sorted, row_start, dis, b2, out);
}

// Round 17
// 259.938 us; speedup vs baseline: 1.8436x; 1.0103x over previous
//
#include <hip/hip_runtime.h>

constexpr int N_NODES = 50000;
constexpr int N_EDGES = 800000;
constexpr float BN_EPS = 1e-5f;
constexpr int BNA_BLOCKS = 256;
constexpr int EBLK = 256;            // edge blocks for radix pass 1
constexpr int EPB = N_EDGES / EBLK;  // 3125 (exact)
constexpr int NBUCK = (N_NODES + 255) / 256;  // 196 row-buckets

typedef __attribute__((ext_vector_type(8))) short short8;
typedef __attribute__((ext_vector_type(4))) float f32x4;
typedef __attribute__((ext_vector_type(2))) float f32x2;

__device__ __forceinline__ float bf2f(ushort u) {
  union { uint i; float f; } v;
  v.i = ((uint)u) << 16;
  return v.f;
}
__device__ __forceinline__ ushort f2bf(float f) {
  union { float f; uint i; } v;
  v.f = f;
  uint r = v.i + 0x7fff + ((v.i >> 16) & 1);  // RNE
  return (ushort)(r >> 16);
}
__device__ __forceinline__ uchar f2fp8(float v) {
  int r = __builtin_amdgcn_cvt_pk_fp8_f32(v, 0.f, 0, false);
  return (uchar)(r & 0xff);
}
__device__ __forceinline__ void dec4(uint w, float* o) {
  f32x2 lo = __builtin_amdgcn_cvt_pk_f32_fp8(w, false);
  f32x2 hi = __builtin_amdgcn_cvt_pk_f32_fp8(w, true);
  o[0] = lo.x;
  o[1] = lo.y;
  o[2] = hi.x;
  o[3] = hi.y;
}

// ================= CSR build: atomic-free 2-pass radix sort by row =================
__global__ __launch_bounds__(256) void k_ehist(const int* __restrict__ erow,
                                               int* __restrict__ bh) {
  __shared__ int h[256];
  int t = threadIdx.x;
  h[t] = 0;
  __syncthreads();
  int base = blockIdx.x * EPB;
  for (int i = t; i < EPB; i += 256) atomicAdd(&h[erow[base + i] >> 8], 1);
  __syncthreads();
  bh[blockIdx.x * 256 + t] = h[t];
}

__global__ void k_binscanA(const int* __restrict__ bh, int* __restrict__ bhoff,
                           int* __restrict__ btot, int nb) {
  __shared__ int s[256];
  int b = blockIdx.x;   // bucket
  int t = threadIdx.x;  // edge-block index
  int v = (t < nb) ? bh[t * 256 + b] : 0;
  s[t] = v;
  __syncthreads();
  for (int off = 1; off < 256; off <<= 1) {
    int x = (t >= off) ? s[t - off] : 0;
    __syncthreads();
    s[t] += x;
    __syncthreads();
  }
  if (t < nb) bhoff[t * 256 + b] = s[t] - v;
  if (t == 255) btot[b] = s[255];
}

__global__ void k_binscanB(const int* __restrict__ btot, int* __restrict__ bucketStart,
                           int* __restrict__ row_start) {
  __shared__ int s[256];
  int t = threadIdx.x;
  int v = btot[t];
  s[t] = v;
  __syncthreads();
  for (int off = 1; off < 256; off <<= 1) {
    int x = (t >= off) ? s[t - off] : 0;
    __syncthreads();
    s[t] += x;
    __syncthreads();
  }
  bucketStart[t] = s[t] - v;  // exclusive
  if (t == 0) row_start[N_NODES] = N_EDGES;
}

__global__ __launch_bounds__(256) void k_escatter(const int* __restrict__ erow,
                                                  const int* __restrict__ ecol,
                                                  const int* __restrict__ bucketStart,
                                                  const int* __restrict__ bhoff,
                                                  int* __restrict__ ebuf) {
  __shared__ int fl[256];
  int t = threadIdx.x;
  fl[t] = 0;
  __syncthreads();
  int b = blockIdx.x, base = b * EPB;
  for (int i = t; i < EPB; i += 256) {
    int r = erow[base + i], c = ecol[base + i];
    int bin = r >> 8;
    int rk = atomicAdd(&fl[bin], 1);
    int pos = bucketStart[bin] + bhoff[b * 256 + bin] + rk;
    ebuf[pos] = ((r & 255) << 16) | c;
  }
}

// pass 3: sort within bucket, emit row_start/deg/dis/col_sorted
__global__ __launch_bounds__(256) void k_esort(const int* __restrict__ ebuf,
                                               const int* __restrict__ bucketStart,
                                               const int* __restrict__ btot,
                                               int* __restrict__ col_sorted,
                                               int* __restrict__ row_start,
                                               float* __restrict__ dis) {
  __shared__ int h[256], pex[256], fl[256], sc[256];
  int bin = blockIdx.x, t = threadIdx.x;
  int base = bucketStart[bin], n = btot[bin];
  h[t] = 0;
  fl[t] = 0;
  __syncthreads();
  for (int i = t; i < n; i += 256) atomicAdd(&h[ebuf[base + i] >> 16], 1);
  __syncthreads();
  int v = h[t];
  sc[t] = v;
  __syncthreads();
  for (int off = 1; off < 256; off <<= 1) {
    int x = (t >= off) ? sc[t - off] : 0;
    __syncthreads();
    sc[t] += x;
    __syncthreads();
  }
  pex[t] = sc[t] - v;  // exclusive prefix within bucket
  int row = bin * 256 + t;
  if (row < N_NODES) {
    row_start[row] = base + pex[t];
    dis[row] = rsqrtf((float)(v + 1));
  }
  __syncthreads();
  for (int i = t; i < n; i += 256) {
    int e = ebuf[base + i];
    int rl = e >> 16;
    int rk = atomicAdd(&fl[rl], 1);
    col_sorted[base + pex[rl] + rk] = e & 0xFFFF;
  }
}

// ---------------- fused W transposes to bf16 ----------------
__global__ void k_wt_all(const float* __restrict__ W0, const float* __restrict__ W1,
                         const float* __restrict__ W2, ushort* __restrict__ Wt0,
                         ushort* __restrict__ Wt1, ushort* __restrict__ Wt2) {
  int idx = blockIdx.x * 256 + threadIdx.x;
  if (idx < 65536) {
    int n = idx >> 8, k = idx & 255;
    Wt0[idx] = f2bf(W0[k * 256 + n]);
  } else if (idx < 131072) {
    int l = idx - 65536;
    int n = l >> 8, k = l & 255;
    Wt1[l] = f2bf(W1[k * 256 + n]);
  } else if (idx < 163840) {
    int l = idx - 131072;
    int n = l >> 8, k = l & 255;  // n in [0,128)
    Wt2[l] = f2bf(W2[k * 128 + n]);
  }
}

// ---------------- bf16 MFMA GEMM, BK=64: hs = cvt( f(A) @ W * d_isqrt ) ----------------
template <int D, bool APPLY_BN, bool OUT_FP8>
__global__ __launch_bounds__(128 * (D / 64)) void k_gemm_bf16(const void* __restrict__ Av,
                                                              const ushort* __restrict__ Wt,
                                                              const float* __restrict__ ss,
                                                              const float* __restrict__ dis,
                                                              void* __restrict__ hsv) {
  constexpr int THREADS = 128 * (D / 64);  // 512 (D=256) / 256 (D=128)
  constexpr int BM = 128, BK = 64, K = 256;
  constexpr int WC = D / 64;
  constexpr int LDP = BK + 8;  // 72 bf16 (144B) stride
  __shared__ ushort As[BM * LDP];
  __shared__ ushort Bs[D * LDP];
  const int tid = threadIdx.x;
  const int lane = tid & 63;
  const int wid = tid >> 6;
  const int wr = wid / WC, wc = wid % WC;
  const int rb = blockIdx.x * BM;

  f32x4 acc[4][4];
#pragma unroll
  for (int m = 0; m < 4; ++m)
#pragma unroll
    for (int n = 0; n < 4; ++n) acc[m][n] = (f32x4)(0.f);

  for (int kt = 0; kt < K; kt += BK) {
    // stage A: 128 rows x 64 k = 1024 short8 tasks
#pragma unroll
    for (int it = 0; it < 1024 / THREADS; ++it) {
      int idx = tid + it * THREADS;
      int row = idx >> 3, kq = idx & 7;
      int gr = rb + row;
      if (gr >= N_NODES) gr = N_NODES - 1;
      float e[8];
      if constexpr (APPLY_BN) {
        const ushort* A = (const ushort*)Av;
        short8 v = *reinterpret_cast<const short8*>(&A[(size_t)gr * K + kt + kq * 8]);
#pragma unroll
        for (int q = 0; q < 8; ++q) {
          int k = kt + kq * 8 + q;
          e[q] = fmaxf(bf2f((ushort)v[q]) * ss[k] + ss[256 + k], 0.f);
        }
      } else {
        const float* A = (const float*)Av;
        const float4* src = reinterpret_cast<const float4*>(&A[(size_t)gr * K + kt + kq * 8]);
        float4 v0 = src[0], v1 = src[1];
        e[0] = v0.x; e[1] = v0.y; e[2] = v0.z; e[3] = v0.w;
        e[4] = v1.x; e[5] = v1.y; e[6] = v1.z; e[7] = v1.w;
      }
      short8 pk;
#pragma unroll
      for (int q = 0; q < 8; ++q) pk[q] = (short)f2bf(e[q]);
      *reinterpret_cast<short8*>(&As[row * LDP + kq * 8]) = pk;
    }
    // stage B: D rows x 64 k = D*8 short8 tasks
#pragma unroll
    for (int it = 0; it < D * 8 / THREADS; ++it) {
      int idx = tid + it * THREADS;
      int n = idx >> 3, kq = idx & 7;
      short8 v = *reinterpret_cast<const short8*>(&Wt[(size_t)n * K + kt + kq * 8]);
      *reinterpret_cast<short8*>(&Bs[n * LDP + kq * 8]) = v;
    }
    __syncthreads();

    const int rl = lane & 15;
#pragma unroll
    for (int ks = 0; ks < 2; ++ks) {
      const int kb = ks * 32 + (lane >> 4) * 8;
      short8 af[4], bfr[4];
#pragma unroll
      for (int f = 0; f < 4; ++f) {
        af[f] = *reinterpret_cast<short8*>(&As[(wr * 64 + f * 16 + rl) * LDP + kb]);
        bfr[f] = *reinterpret_cast<short8*>(&Bs[(wc * 64 + f * 16 + rl) * LDP + kb]);
      }
#pragma unroll
      for (int m = 0; m < 4; ++m)
#pragma unroll
        for (int n = 0; n < 4; ++n)
          acc[m][n] = __builtin_amdgcn_mfma_f32_16x16x32_bf16(af[m], bfr[n], acc[m][n], 0, 0, 0);
    }
    __syncthreads();
  }

  const int cl = lane & 15;
  const int rq = lane >> 4;
#pragma unroll
  for (int m = 0; m < 4; ++m) {
    int rbase = rb + wr * 64 + m * 16 + rq * 4;
#pragma unroll
    for (int j = 0; j < 4; ++j) {
      int row = rbase + j;
      if (row >= N_NODES) continue;
      float di = dis[row];
#pragma unroll
      for (int n = 0; n < 4; ++n) {
        int col = wc * 64 + n * 16 + cl;
        if constexpr (OUT_FP8) {
          ((uchar*)hsv)[(size_t)row * D + col] = f2fp8(acc[m][n][j] * di);
        } else {
          ((ushort*)hsv)[(size_t)row * D + col] = f2bf(acc[m][n][j] * di);
        }
      }
    }
  }
}

// ---------------- fp8 aggregation: pre = bf16(dis*(self+sum_nbr)+b) ----------------
__global__ __launch_bounds__(256) void k_agg_fp8(const uchar* __restrict__ hs8,
                                                 const int* __restrict__ cs,
                                                 const int* __restrict__ rs,
                                                 const float* __restrict__ dis,
                                                 const float* __restrict__ bias,
                                                 ushort* __restrict__ pre) {
  int gw = (blockIdx.x * 256 + threadIdx.x) >> 6;
  if (gw >= N_NODES) return;
  const int lane = threadIdx.x & 63;
  const int quad = lane >> 4;
  const int c16 = lane & 15;
  const size_t coff = (size_t)c16 * 16;

  float a[16];
  {
    uint4 sv = *reinterpret_cast<const uint4*>(&hs8[(size_t)gw * 256 + coff]);
    float tmp[16];
    dec4(sv.x, tmp);
    dec4(sv.y, tmp + 4);
    dec4(sv.z, tmp + 8);
    dec4(sv.w, tmp + 12);
#pragma unroll
    for (int q = 0; q < 16; ++q) a[q] = quad ? 0.f : tmp[q];
  }

  int s = rs[gw], e = rs[gw + 1];
  for (int base = s; base < e; base += 64) {
    int nav = min(64, e - base);
    int idx = (base + lane < e) ? cs[base + lane] : 0;
    int j = 0;
    for (; j + 16 <= nav; j += 16) {  // 16 edges: 4 loads in flight
      uint4 v[4];
#pragma unroll
      for (int u = 0; u < 4; ++u) {
        int c = __shfl(idx, j + 4 * u + quad);
        v[u] = *reinterpret_cast<const uint4*>(&hs8[(size_t)((uint)c) * 256 + coff]);
      }
#pragma unroll
      for (int u = 0; u < 4; ++u) {
        float tmp[16];
        dec4(v[u].x, tmp);
        dec4(v[u].y, tmp + 4);
        dec4(v[u].z, tmp + 8);
        dec4(v[u].w, tmp + 12);
#pragma unroll
        for (int q = 0; q < 16; ++q) a[q] += tmp[q];
      }
    }
    for (; j < nav; j += 4) {  // tail: weight-folded quad-load
      int je = j + quad;
      int c = __shfl(idx, je & 63);
      float w = (je < nav) ? 1.f : 0.f;
      uint4 v = *reinterpret_cast<const uint4*>(&hs8[(size_t)((uint)c) * 256 + coff]);
      float tmp[16];
      dec4(v.x, tmp);
      dec4(v.y, tmp + 4);
      dec4(v.z, tmp + 8);
      dec4(v.w, tmp + 12);
#pragma unroll
      for (int q = 0; q < 16; ++q) a[q] = fmaf(w, tmp[q], a[q]);
    }
  }
#pragma unroll
  for (int q = 0; q < 16; ++q) {
    a[q] += __shfl_xor(a[q], 16);
    a[q] += __shfl_xor(a[q], 32);
  }

  if (quad == 0) {
    float di = dis[gw];
    float bb[16];
#pragma unroll
    for (int p = 0; p < 4; ++p) {
      float4 b = *reinterpret_cast<const float4*>(&bias[coff + p * 4]);
      bb[p * 4] = b.x;
      bb[p * 4 + 1] = b.y;
      bb[p * 4 + 2] = b.z;
      bb[p * 4 + 3] = b.w;
    }
    short8 o0, o1;
#pragma unroll
    for (int q = 0; q < 8; ++q) {
      o0[q] = (short)f2bf(a[q] * di + bb[q]);
      o1[q] = (short)f2bf(a[8 + q] * di + bb[8 + q]);
    }
    *reinterpret_cast<short8*>(&pre[(size_t)gw * 256 + coff]) = o0;
    *reinterpret_cast<short8*>(&pre[(size_t)gw * 256 + coff + 8]) = o1;
  }
}

// layer-3 agg + log_softmax: D=128 bf16 row = 256B = 16 lanes x short8; 4 edges/instr.
__global__ __launch_bounds__(256) void k_agg_lsm_bf16(const ushort* __restrict__ hs,
                                                      const int* __restrict__ cs,
                                                      const int* __restrict__ rs,
                                                      const float* __restrict__ dis,
                                                      const float* __restrict__ bias,
                                                      float* __restrict__ out) {
  int gw = (blockIdx.x * 256 + threadIdx.x) >> 6;
  if (gw >= N_NODES) return;
  const int lane = threadIdx.x & 63;
  const int quad = lane >> 4;
  const int c8 = lane & 15;
  const size_t coff = (size_t)c8 * 8;

  float a[8];
  short8 sv = *reinterpret_cast<const short8*>(&hs[(size_t)gw * 128 + coff]);
#pragma unroll
  for (int q = 0; q < 8; ++q) a[q] = quad ? 0.f : bf2f((ushort)sv[q]);

  int s = rs[gw], e = rs[gw + 1];
  for (int base = s; base < e; base += 64) {
    int nav = min(64, e - base);
    int idx = (base + lane < e) ? cs[base + lane] : 0;
    int j = 0;
    for (; j + 16 <= nav; j += 16) {
      short8 v[4];
#pragma unroll
      for (int u = 0; u < 4; ++u) {
        int c = __shfl(idx, j + 4 * u + quad);
        v[u] = *reinterpret_cast<const short8*>(&hs[(size_t)((uint)c) * 128 + coff]);
      }
#pragma unroll
      for (int u = 0; u < 4; ++u)
#pragma unroll
        for (int q = 0; q < 8; ++q) a[q] += bf2f((ushort)v[u][q]);
    }
    for (; j < nav; j += 4) {
      int je = j + quad;
      int c = __shfl(idx, je & 63);
      float w = (je < nav) ? 1.f : 0.f;
      short8 v = *reinterpret_cast<const short8*>(&hs[(size_t)((uint)c) * 128 + coff]);
#pragma unroll
      for (int q = 0; q < 8; ++q) a[q] = fmaf(w, bf2f((ushort)v[q]), a[q]);
    }
  }
#pragma unroll
  for (int q = 0; q < 8; ++q) {
    a[q] += __shfl_xor(a[q], 16);
    a[q] += __shfl_xor(a[q], 32);
  }

  float di = dis[gw];
  float4 b0 = *reinterpret_cast<const float4*>(&bias[c8 * 8]);
  float4 b1 = *reinterpret_cast<const float4*>(&bias[c8 * 8 + 4]);
  float bb[8] = {b0.x, b0.y, b0.z, b0.w, b1.x, b1.y, b1.z, b1.w};
  float vv[8];
  float m = -1e30f;
#pragma unroll
  for (int q = 0; q < 8; ++q) {
    vv[q] = a[q] * di + bb[q];
    m = fmaxf(m, vv[q]);
  }
#pragma unroll
  for (int o = 1; o < 16; o <<= 1) m = fmaxf(m, __shfl_xor(m, o));
  float sum = 0.f;
#pragma unroll
  for (int q = 0; q < 8; ++q) sum += __expf(vv[q] - m);
#pragma unroll
  for (int o = 1; o < 16; o <<= 1) sum += __shfl_xor(sum, o);
  float ls = m + logf(sum);
  if (quad == 0) {
    float4 o0 = {vv[0] - ls, vv[1] - ls, vv[2] - ls, vv[3] - ls};
    float4 o1 = {vv[4] - ls, vv[5] - ls, vv[6] - ls, vv[7] - ls};
    *reinterpret_cast<float4*>(&out[(size_t)gw * 128 + coff]) = o0;
    *reinterpret_cast<float4*>(&out[(size_t)gw * 128 + coff + 4]) = o1;
  }
}

// ---------------- batchnorm stats: three-phase, atomic-free ----------------
__global__ __launch_bounds__(256) void k_bnstatsA(const ushort* __restrict__ pre,
                                                  float* __restrict__ partial) {
  int t = threadIdx.x;
  int rsub = t >> 7;
  int cp = (t & 127) * 2;
  float s0 = 0.f, s1 = 0.f, q0 = 0.f, q1 = 0.f;
  for (int r = blockIdx.x * 2 + rsub; r < N_NODES; r += BNA_BLOCKS * 2) {
    ushort2 v = *reinterpret_cast<const ushort2*>(&pre[(size_t)r * 256 + cp]);
    float f0 = bf2f(v.x), f1 = bf2f(v.y);
    s0 += f0;
    q0 += f0 * f0;
    s1 += f1;
    q1 += f1 * f1;
  }
  __shared__ float lsum[256], lsq[256];
  if (rsub) {
    lsum[cp] = s0;
    lsum[cp + 1] = s1;
    lsq[cp] = q0;
    lsq[cp + 1] = q1;
  }
  __syncthreads();
  if (!rsub) {
    float* p = &partial[(size_t)blockIdx.x * 512];
    p[cp] = s0 + lsum[cp];
    p[cp + 1] = s1 + lsum[cp + 1];
    p[256 + cp] = q0 + lsq[cp];
    p[256 + cp + 1] = q1 + lsq[cp + 1];
  }
}

__global__ __launch_bounds__(512) void k_bnstatsB(const float* __restrict__ partial,
                                                  float* __restrict__ p2) {
  int t = threadIdx.x, b = blockIdx.x;
  float a = 0.f;
#pragma unroll 8
  for (int r = 0; r < BNA_BLOCKS / 8; ++r)
    a += partial[(size_t)(b * (BNA_BLOCKS / 8) + r) * 512 + t];
  p2[(size_t)b * 512 + t] = a;
}

__global__ void k_bnfinal(const float* __restrict__ p2, const float* __restrict__ gamma,
                          const float* __restrict__ beta, float* __restrict__ ss) {
  int t = threadIdx.x;
  float sum = 0.f, sq = 0.f;
#pragma unroll
  for (int b = 0; b < 8; ++b) {
    sum += p2[(size_t)b * 512 + t];
    sq += p2[(size_t)b * 512 + 256 + t];
  }
  float mu = sum * (1.f / N_NODES);
  float var = sq * (1.f / N_NODES) - mu * mu;
  float sc = gamma[t] * rsqrtf(var + BN_EPS);
  ss[t] = sc;
  ss[256 + t] = beta[t] - mu * sc;
}

// ---------------- launcher ----------------
extern "C" void kernel_launch(void* const* d_in, const int* in_sizes, int n_in,
                              void* d_out, int out_size, void* d_ws, size_t ws_size,
                              hipStream_t stream) {
  const float* x = (const float*)d_in[0];
  const int* erow = (const int*)d_in[1];
  const int* ecol = erow + N_EDGES;
  const float* W0 = (const float*)d_in[2];
  const float* b0 = (const float*)d_in[3];
  const float* W1 = (const float*)d_in[4];
  const float* b1 = (const float*)d_in[5];
  const float* W2 = (const float*)d_in[6];
  const float* b2 = (const float*)d_in[7];
  const float* g0 = (const float*)d_in[8];
  const float* be0 = (const float*)d_in[9];
  const float* g1 = (const float*)d_in[10];
  const float* be1 = (const float*)d_in[11];
  float* out = (float*)d_out;

  char* ws = (char*)d_ws;
  size_t off = 0;
  auto take = [&](size_t bytes) {
    char* p = ws + off;
    off = (off + bytes + 255) & ~(size_t)255;
    return p;
  };
  int* bh = (int*)take(256 * 256 * 4);
  int* bhoff = (int*)take(256 * 256 * 4);
  int* btot = (int*)take(256 * 4);
  int* bucketStart = (int*)take(256 * 4);
  int* ebuf = (int*)take((size_t)N_EDGES * 4);
  int* row_start = (int*)take((N_NODES + 1) * 4);
  float* bnpart = (float*)take((size_t)BNA_BLOCKS * 512 * 4);
  float* bnpart2 = (float*)take(8 * 512 * 4);
  float* dis = (float*)take(N_NODES * 4);
  float* ss0 = (float*)take(512 * 4);
  float* ss1 = (float*)take(512 * 4);
  ushort* Wt0 = (ushort*)take(256 * 256 * 2);
  ushort* Wt1 = (ushort*)take(256 * 256 * 2);
  ushort* Wt2 = (ushort*)take(256 * 128 * 2);
  int* col_sorted = (int*)take((size_t)N_EDGES * 4);
  uchar* hs8 = (uchar*)take((size_t)N_NODES * 256);        // fp8 gather operand (L0/L1)
  ushort* hs = (ushort*)take((size_t)N_NODES * 128 * 2);   // bf16 (L2)
  ushort* pre = (ushort*)take((size_t)N_NODES * 256 * 2);  // bf16
  if (off > ws_size) return;

  // CSR build: radix sort by row, no global atomics, no memset
  k_ehist<<<EBLK, 256, 0, stream>>>(erow, bh);
  k_binscanA<<<256, 256, 0, stream>>>(bh, bhoff, btot, EBLK);
  k_binscanB<<<1, 256, 0, stream>>>(btot, bucketStart, row_start);
  k_escatter<<<EBLK, 256, 0, stream>>>(erow, ecol, bucketStart, bhoff, ebuf);
  k_esort<<<NBUCK, 256, 0, stream>>>(ebuf, bucketStart, btot, col_sorted, row_start, dis);

  k_wt_all<<<640, 256, 0, stream>>>(W0, W1, W2, Wt0, Wt1, Wt2);

  int mblocks = (N_NODES + 127) / 128;        // 391
  int agg_grid = (N_NODES * 64 + 255) / 256;  // 12500
  // layer 0 (hs fp8)
  k_gemm_bf16<256, false, true><<<mblocks, 512, 0, stream>>>(x, Wt0, nullptr, dis, hs8);
  k_agg_fp8<<<agg_grid, 256, 0, stream>>>(hs8, col_sorted, row_start, dis, b0, pre);
  k_bnstatsA<<<BNA_BLOCKS, 256, 0, stream>>>(pre, bnpart);
  k_bnstatsB<<<8, 512, 0, stream>>>(bnpart, bnpart2);
  k_bnfinal<<<1, 256, 0, stream>>>(bnpart2, g0, be0, ss0);
  // layer 1 (hs fp8)
  k_gemm_bf16<256, true, true><<<mblocks, 512, 0, stream>>>(pre, Wt1, ss0, dis, hs8);
  k_agg_fp8<<<agg_grid, 256, 0, stream>>>(hs8, col_sorted, row_start, dis, b1, pre);
  k_bnstatsA<<<BNA_BLOCKS, 256, 0, stream>>>(pre, bnpart);
  k_bnstatsB<<<8, 512, 0, stream>>>(bnpart, bnpart2);
  k_bnfinal<<<1, 256, 0, stream>>>(bnpart2, g1, be1, ss1);
  // layer 2 (bf16) + fused log_softmax
  k_gemm_bf16<128, true, false><<<mblocks, 256, 0, stream>>>(pre, Wt2, ss1, dis, hs);
  k_agg_lsm_bf16<<<agg_grid, 256, 0, stream>>>(hs, col_sorted, row_start, dis, b2, out);
}